// Round 1
// baseline (617.879 us; speedup 1.0000x reference)
//
#include <hip/hip_runtime.h>

#define EMB 64
#define HID 256

// ---------------------------------------------------------------------------
// SpMM: x[r] += val[e] * emb[col[e]]  (one wave per edge, lane = emb dim)
// ---------------------------------------------------------------------------
__global__ __launch_bounds__(256) void spmm_kernel(
    const int* __restrict__ row, const int* __restrict__ col,
    const float* __restrict__ val, const float* __restrict__ emb,
    float* __restrict__ x, int E)
{
    int gid  = blockIdx.x * blockDim.x + threadIdx.x;
    int e    = gid >> 6;
    int lane = gid & 63;
    if (e >= E) return;
    int   r = row[e];
    int   c = col[e];
    float v = val[e];
    unsafeAtomicAdd(&x[(size_t)r * EMB + lane], v * emb[(size_t)c * EMB + lane]);
}

// ---------------------------------------------------------------------------
// C[M x 256] = relu?(A[M x K] @ B[K x 256])
// block = 256 threads, tile BM=64 x BN=256 (full width), BK=16
// thread (tm = t>>4, tn = t&15) computes rows m4..m4+3, cols tn*4 + j*64 (+q)
// In-place safe (A == C allowed): each block reads only its own 64 rows and
// stores only in the epilogue after all loads.
// ---------------------------------------------------------------------------
template<int K, bool RELU>
__global__ __launch_bounds__(256) void gemm_kernel(
    const float* A, const float* __restrict__ B, float* C, int M)
{
    __shared__ float As[64][17];    // [m][k], +1 pad: conflict-free reads
    __shared__ float Bs[16][256];   // [k][n]

    const int t    = threadIdx.x;
    const int tn   = t & 15;
    const int tm   = t >> 4;
    const int m4   = (t >> 4) & ~0;           // 0..15 -> rows m4*? see below
    const int row0 = blockIdx.x * 64;

    // staging ids
    const int sk = t & 15;          // k within BK for A staging
    const int sm = (t >> 4) * 4;    // 4 rows per thread for A staging

    float acc[4][16];
#pragma unroll
    for (int i = 0; i < 4; ++i)
#pragma unroll
        for (int j = 0; j < 16; ++j) acc[i][j] = 0.f;

    const int mB = ((t & 63) >> 4) * 4;   // wave-local row group 0,4,8,12
    const int wq = t >> 6;                // wave id 0..3
    const int myM = (wq * 16) + mB;       // rows this thread accumulates: myM..myM+3

    for (int k0 = 0; k0 < K; k0 += 16) {
        __syncthreads();
        // stage A tile (64 x 16) -> As[m][k]
#pragma unroll
        for (int i = 0; i < 4; ++i) {
            int m  = sm + i;
            int gr = row0 + m;
            As[m][sk] = (gr < M) ? A[(size_t)gr * K + k0 + sk] : 0.f;
        }
        // stage B tile (16 x 256) -> Bs[k][n]
#pragma unroll
        for (int r = 0; r < 16; ++r) {
            Bs[r][t] = B[(size_t)(k0 + r) * 256 + t];
        }
        __syncthreads();

#pragma unroll
        for (int kk = 0; kk < 16; ++kk) {
            float a0 = As[myM + 0][kk];
            float a1 = As[myM + 1][kk];
            float a2 = As[myM + 2][kk];
            float a3 = As[myM + 3][kk];
            float4 b[4];
#pragma unroll
            for (int j = 0; j < 4; ++j)
                b[j] = *(const float4*)&Bs[kk][tn * 4 + j * 64];
#pragma unroll
            for (int j = 0; j < 4; ++j) {
                acc[0][j*4+0] += a0 * b[j].x;  acc[0][j*4+1] += a0 * b[j].y;
                acc[0][j*4+2] += a0 * b[j].z;  acc[0][j*4+3] += a0 * b[j].w;
                acc[1][j*4+0] += a1 * b[j].x;  acc[1][j*4+1] += a1 * b[j].y;
                acc[1][j*4+2] += a1 * b[j].z;  acc[1][j*4+3] += a1 * b[j].w;
                acc[2][j*4+0] += a2 * b[j].x;  acc[2][j*4+1] += a2 * b[j].y;
                acc[2][j*4+2] += a2 * b[j].z;  acc[2][j*4+3] += a2 * b[j].w;
                acc[3][j*4+0] += a3 * b[j].x;  acc[3][j*4+1] += a3 * b[j].y;
                acc[3][j*4+2] += a3 * b[j].z;  acc[3][j*4+3] += a3 * b[j].w;
            }
        }
    }

    // epilogue
#pragma unroll
    for (int i = 0; i < 4; ++i) {
        int gr = row0 + myM + i;
        if (gr < M) {
#pragma unroll
            for (int j = 0; j < 4; ++j) {
                float4 o;
                o.x = acc[i][j*4+0]; o.y = acc[i][j*4+1];
                o.z = acc[i][j*4+2]; o.w = acc[i][j*4+3];
                if (RELU) {
                    o.x = fmaxf(o.x, 0.f); o.y = fmaxf(o.y, 0.f);
                    o.z = fmaxf(o.z, 0.f); o.w = fmaxf(o.w, 0.f);
                }
                *(float4*)&C[(size_t)gr * 256 + tn * 4 + j * 64] = o;
            }
        }
    }
}

extern "C" void kernel_launch(void* const* d_in, const int* in_sizes, int n_in,
                              void* d_out, int out_size, void* d_ws, size_t ws_size,
                              hipStream_t stream)
{
    const int*   row = (const int*)d_in[0];
    const int*   col = (const int*)d_in[1];
    const float* val = (const float*)d_in[2];
    const float* emb = (const float*)d_in[3];
    const float* W0  = (const float*)d_in[4];
    const float* W1  = (const float*)d_in[5];
    const float* W2  = (const float*)d_in[6];
    float* out = (float*)d_out;

    const int E = in_sizes[0];
    const int M = in_sizes[3] / EMB;   // num nodes

    float* x = (float*)d_ws;           // [M x 64] SpMM output

    // zero the SpMM accumulator
    hipMemsetAsync(x, 0, (size_t)M * EMB * sizeof(float), stream);

    // SpMM: one wave per edge
    {
        int waves  = E;
        int blocks = (waves + 3) / 4;  // 4 waves (256 thr) per block
        spmm_kernel<<<blocks, 256, 0, stream>>>(row, col, val, emb, x, E);
    }

    int gblocks = (M + 63) / 64;
    // h0 = relu(x @ W0)        -> d_out (scratch)
    gemm_kernel<EMB, true ><<<gblocks, 256, 0, stream>>>(x,   W0, out, M);
    // h1 = relu(h0 @ W1)       -> d_out in-place
    gemm_kernel<HID, true ><<<gblocks, 256, 0, stream>>>(out, W1, out, M);
    // out = h1 @ W2            -> d_out in-place
    gemm_kernel<HID, false><<<gblocks, 256, 0, stream>>>(out, W2, out, M);
}

// Round 3
// 276.371 us; speedup vs baseline: 2.2357x; 2.2357x over previous
//
#include <hip/hip_runtime.h>
#include <hip/hip_bf16.h>

#define EMB 64
#define HID 256

typedef __attribute__((ext_vector_type(8))) short short8_t;   // 8 bf16 = 4 VGPRs
typedef __attribute__((ext_vector_type(4))) float f32x4;

// fp32 -> bf16 bits, round-to-nearest-even (matches HW conversion)
__device__ __forceinline__ unsigned short f2bf(float f)
{
    union { float f; unsigned int u; } c; c.f = f;
    unsigned int u = c.u;
    u += 0x7fffu + ((u >> 16) & 1u);
    return (unsigned short)(u >> 16);
}

// ---------------------------------------------------------------------------
// SpMM: x[r] += val[e] * emb[col[e]]  (one wave per edge, lane = emb dim)
// ---------------------------------------------------------------------------
__global__ __launch_bounds__(256) void spmm_kernel(
    const int* __restrict__ row, const int* __restrict__ col,
    const float* __restrict__ val, const float* __restrict__ emb,
    float* __restrict__ x, int E)
{
    int gid  = blockIdx.x * blockDim.x + threadIdx.x;
    int e    = gid >> 6;
    int lane = gid & 63;
    if (e >= E) return;
    int   r = row[e];
    int   c = col[e];
    float v = val[e];
    unsafeAtomicAdd(&x[(size_t)r * EMB + lane], v * emb[(size_t)c * EMB + lane]);
}

// ---------------------------------------------------------------------------
// convert fp32 -> bf16, 4 elems/thread (n must be multiple of 4)
// ---------------------------------------------------------------------------
__global__ __launch_bounds__(256) void cvt_f32_bf16(
    const float* __restrict__ in, unsigned short* __restrict__ out, int n)
{
    int idx = (blockIdx.x * blockDim.x + threadIdx.x) * 4;
    if (idx >= n) return;
    float4 v = *(const float4*)&in[idx];
    ushort4 o;
    o.x = f2bf(v.x);
    o.y = f2bf(v.y);
    o.z = f2bf(v.z);
    o.w = f2bf(v.w);
    *(ushort4*)&out[idx] = o;
}

// ---------------------------------------------------------------------------
// transpose + convert: in fp32 [K][256] -> out bf16 [256][K]
// ---------------------------------------------------------------------------
__global__ __launch_bounds__(256) void transpose_cvt(
    const float* __restrict__ in, unsigned short* __restrict__ out, int K)
{
    int i = blockIdx.x * 256 + threadIdx.x;
    if (i >= K * 256) return;
    int k = i >> 8;
    int n = i & 255;
    out[(size_t)n * K + k] = f2bf(in[i]);
}

// ---------------------------------------------------------------------------
// MFMA GEMM: C[M x 256] = relu?(A[M x K] @ B[K x 256]),  B given as Bt[256][K]
// block = 256 threads (4 waves), BM=64, BN=256, BK=64
// wave w owns cols [w*64, w*64+64); 4x4 tiles of 16x16 per wave.
// In-place safe (A may alias C): all global A-reads complete before the
// pre-compute __syncthreads of the last K-step; stores only in epilogue.
// ---------------------------------------------------------------------------
template<int K, bool RELU, bool OUT_BF16>
__global__ __launch_bounds__(256) void gemm_mfma(
    const unsigned short* A, const unsigned short* __restrict__ Bt,
    void* Cv, int M)
{
    constexpr int BK  = 64;
    constexpr int LDA = BK + 8;                // 72 bf16 = 144B padded stride
    __shared__ unsigned short As[64 * LDA];
    __shared__ unsigned short Bs[256 * LDA];

    const int t    = threadIdx.x;
    const int lane = t & 63;
    const int w    = t >> 6;                   // wave 0..3
    const int lr   = lane & 15;                // row (A) / col (B) within tile
    const int kg   = lane >> 4;                // k-group 0..3
    const int row0 = blockIdx.x * 64;

    f32x4 acc[4][4] = {};                      // [m-tile][n-tile]

    for (int k0 = 0; k0 < K; k0 += BK) {
        __syncthreads();
        // stage A tile: 64 rows x 64 k  (512 x 16B chunks, 2 per thread)
#pragma unroll
        for (int c = 0; c < 2; ++c) {
            int chunk = t + c * 256;
            int r  = chunk >> 3;
            int ko = (chunk & 7) * 8;
            int gr = row0 + r;
            const unsigned short* src = A + (size_t)(gr < M ? gr : 0) * K + k0 + ko;
            *(short8_t*)&As[r * LDA + ko] = *(const short8_t*)src;
        }
        // stage B tile: 256 n-rows x 64 k (2048 x 16B chunks, 8 per thread)
#pragma unroll
        for (int c = 0; c < 8; ++c) {
            int chunk = t + c * 256;
            int n  = chunk >> 3;
            int ko = (chunk & 7) * 8;
            *(short8_t*)&Bs[n * LDA + ko] =
                *(const short8_t*)(Bt + (size_t)n * K + k0 + ko);
        }
        __syncthreads();

#pragma unroll
        for (int ks = 0; ks < BK; ks += 32) {
            short8_t a[4], b[4];
#pragma unroll
            for (int m = 0; m < 4; ++m)
                a[m] = *(const short8_t*)&As[(m * 16 + lr) * LDA + ks + kg * 8];
#pragma unroll
            for (int n = 0; n < 4; ++n)
                b[n] = *(const short8_t*)&Bs[(w * 64 + n * 16 + lr) * LDA + ks + kg * 8];
#pragma unroll
            for (int m = 0; m < 4; ++m)
#pragma unroll
                for (int n = 0; n < 4; ++n)
                    acc[m][n] = __builtin_amdgcn_mfma_f32_16x16x32_bf16(
                        a[m], b[n], acc[m][n], 0, 0, 0);
        }
    }

    // epilogue: D mapping col = lane&15, row = (lane>>4)*4 + reg
#pragma unroll
    for (int m = 0; m < 4; ++m) {
#pragma unroll
        for (int r = 0; r < 4; ++r) {
            int gr = row0 + m * 16 + kg * 4 + r;
            if (gr < M) {
#pragma unroll
                for (int n = 0; n < 4; ++n) {
                    float v = acc[m][n][r];
                    if (RELU) v = fmaxf(v, 0.f);
                    int gc = w * 64 + n * 16 + lr;
                    if (OUT_BF16)
                        ((unsigned short*)Cv)[(size_t)gr * 256 + gc] = f2bf(v);
                    else
                        ((float*)Cv)[(size_t)gr * 256 + gc] = v;
                }
            }
        }
    }
}

// ---------------------------------------------------------------------------
// fp32 fallback GEMM (round-1 kernel) — used only if ws_size is too small
// ---------------------------------------------------------------------------
template<int K, bool RELU>
__global__ __launch_bounds__(256) void gemm_f32(
    const float* A, const float* __restrict__ B, float* C, int M)
{
    __shared__ float As[64][17];
    __shared__ float Bs[16][256];

    const int t    = threadIdx.x;
    const int tn   = t & 15;
    const int row0 = blockIdx.x * 64;
    const int sk = t & 15;
    const int sm = (t >> 4) * 4;

    float acc[4][16];
#pragma unroll
    for (int i = 0; i < 4; ++i)
#pragma unroll
        for (int j = 0; j < 16; ++j) acc[i][j] = 0.f;

    const int mB = ((t & 63) >> 4) * 4;
    const int wq = t >> 6;
    const int myM = (wq * 16) + mB;

    for (int k0 = 0; k0 < K; k0 += 16) {
        __syncthreads();
#pragma unroll
        for (int i = 0; i < 4; ++i) {
            int m  = sm + i;
            int gr = row0 + m;
            As[m][sk] = (gr < M) ? A[(size_t)gr * K + k0 + sk] : 0.f;
        }
#pragma unroll
        for (int r = 0; r < 16; ++r)
            Bs[r][t] = B[(size_t)(k0 + r) * 256 + t];
        __syncthreads();

#pragma unroll
        for (int kk = 0; kk < 16; ++kk) {
            float a0 = As[myM + 0][kk];
            float a1 = As[myM + 1][kk];
            float a2 = As[myM + 2][kk];
            float a3 = As[myM + 3][kk];
            float4 b[4];
#pragma unroll
            for (int j = 0; j < 4; ++j)
                b[j] = *(const float4*)&Bs[kk][tn * 4 + j * 64];
#pragma unroll
            for (int j = 0; j < 4; ++j) {
                acc[0][j*4+0] += a0 * b[j].x;  acc[0][j*4+1] += a0 * b[j].y;
                acc[0][j*4+2] += a0 * b[j].z;  acc[0][j*4+3] += a0 * b[j].w;
                acc[1][j*4+0] += a1 * b[j].x;  acc[1][j*4+1] += a1 * b[j].y;
                acc[1][j*4+2] += a1 * b[j].z;  acc[1][j*4+3] += a1 * b[j].w;
                acc[2][j*4+0] += a2 * b[j].x;  acc[2][j*4+1] += a2 * b[j].y;
                acc[2][j*4+2] += a2 * b[j].z;  acc[2][j*4+3] += a2 * b[j].w;
                acc[3][j*4+0] += a3 * b[j].x;  acc[3][j*4+1] += a3 * b[j].y;
                acc[3][j*4+2] += a3 * b[j].z;  acc[3][j*4+3] += a3 * b[j].w;
            }
        }
    }

#pragma unroll
    for (int i = 0; i < 4; ++i) {
        int gr = row0 + myM + i;
        if (gr < M) {
#pragma unroll
            for (int j = 0; j < 4; ++j) {
                float4 o;
                o.x = acc[i][j*4+0]; o.y = acc[i][j*4+1];
                o.z = acc[i][j*4+2]; o.w = acc[i][j*4+3];
                if (RELU) {
                    o.x = fmaxf(o.x, 0.f); o.y = fmaxf(o.y, 0.f);
                    o.z = fmaxf(o.z, 0.f); o.w = fmaxf(o.w, 0.f);
                }
                *(float4*)&C[(size_t)gr * 256 + tn * 4 + j * 64] = o;
            }
        }
    }
}

extern "C" void kernel_launch(void* const* d_in, const int* in_sizes, int n_in,
                              void* d_out, int out_size, void* d_ws, size_t ws_size,
                              hipStream_t stream)
{
    const int*   row = (const int*)d_in[0];
    const int*   col = (const int*)d_in[1];
    const float* val = (const float*)d_in[2];
    const float* emb = (const float*)d_in[3];
    const float* W0  = (const float*)d_in[4];
    const float* W1  = (const float*)d_in[5];
    const float* W2  = (const float*)d_in[6];
    float* out = (float*)d_out;

    const int E = in_sizes[0];
    const int M = in_sizes[3] / EMB;   // num nodes

    char* ws = (char*)d_ws;
    // ws layout (bytes)
    const size_t off_x  = 0;                            // fp32 [M][64]
    const size_t off_xb = off_x  + (size_t)M * 64 * 4;  // bf16 [M][64]
    const size_t off_h  = off_xb + (size_t)M * 64 * 2;  // bf16 [M][256] (h0 then h1 in-place)
    const size_t off_w0 = off_h  + (size_t)M * 256 * 2; // bf16 [256][64]
    const size_t off_w1 = off_w0 + (size_t)64  * 256 * 2;
    const size_t off_w2 = off_w1 + (size_t)256 * 256 * 2;
    const size_t need   = off_w2 + (size_t)256 * 256 * 2;

    float* x = (float*)(ws + off_x);

    // zero the SpMM accumulator
    (void)hipMemsetAsync(x, 0, (size_t)M * EMB * sizeof(float), stream);

    // SpMM: one wave per edge
    {
        int blocks = (E + 3) / 4;      // 4 waves (256 thr) per block
        spmm_kernel<<<blocks, 256, 0, stream>>>(row, col, val, emb, x, E);
    }

    int gblocks = (M + 63) / 64;

    if (ws_size >= need) {
        unsigned short* xb  = (unsigned short*)(ws + off_xb);
        unsigned short* h   = (unsigned short*)(ws + off_h);
        unsigned short* W0t = (unsigned short*)(ws + off_w0);
        unsigned short* W1t = (unsigned short*)(ws + off_w1);
        unsigned short* W2t = (unsigned short*)(ws + off_w2);

        // weight prep (tiny)
        transpose_cvt<<<(64  * 256 + 255) / 256, 256, 0, stream>>>(W0, W0t, 64);
        transpose_cvt<<<(256 * 256 + 255) / 256, 256, 0, stream>>>(W1, W1t, 256);
        transpose_cvt<<<(256 * 256 + 255) / 256, 256, 0, stream>>>(W2, W2t, 256);

        // x -> bf16
        int ncvt = M * 64;
        cvt_f32_bf16<<<(ncvt / 4 + 255) / 256, 256, 0, stream>>>(x, xb, ncvt);

        // h0 = relu(xb @ W0)   -> h (bf16)
        gemm_mfma<EMB, true,  true ><<<gblocks, 256, 0, stream>>>(xb, W0t, h, M);
        // h1 = relu(h0 @ W1)   -> h in-place (bf16)
        gemm_mfma<HID, true,  true ><<<gblocks, 256, 0, stream>>>(h,  W1t, h, M);
        // out = h1 @ W2        -> d_out (fp32)
        gemm_mfma<HID, false, false><<<gblocks, 256, 0, stream>>>(h,  W2t, out, M);
    } else {
        // fp32 fallback (ws too small for bf16 pipeline)
        gemm_f32<EMB, true ><<<gblocks, 256, 0, stream>>>(x,   W0, out, M);
        gemm_f32<HID, true ><<<gblocks, 256, 0, stream>>>(out, W1, out, M);
        gemm_f32<HID, false><<<gblocks, 256, 0, stream>>>(out, W2, out, M);
    }
}

// Round 4
// 263.522 us; speedup vs baseline: 2.3447x; 1.0488x over previous
//
#include <hip/hip_runtime.h>
#include <hip/hip_bf16.h>

#define EMB 64
#define HID 256

typedef __attribute__((ext_vector_type(8))) short short8_t;   // 8 bf16 = 4 VGPRs
typedef __attribute__((ext_vector_type(4))) float f32x4;

// fp32 -> bf16 bits, round-to-nearest-even (matches HW conversion)
__device__ __forceinline__ unsigned short f2bf(float f)
{
    union { float f; unsigned int u; } c; c.f = f;
    unsigned int u = c.u;
    u += 0x7fffu + ((u >> 16) & 1u);
    return (unsigned short)(u >> 16);
}

// ---------------------------------------------------------------------------
// CSR build: histogram -> exclusive scan -> bucket scatter
// ---------------------------------------------------------------------------
__global__ __launch_bounds__(256) void hist_kernel(
    const int* __restrict__ row, int* __restrict__ counts, int E)
{
    int e = blockIdx.x * 256 + threadIdx.x;
    if (e < E) atomicAdd(&counts[row[e]], 1);
}

// phase1: per-block (1024 elems) exclusive scan; block total -> blockSums
__global__ __launch_bounds__(256) void scan_phase1(
    const int* __restrict__ counts, int* __restrict__ excl,
    int* __restrict__ blockSums, int n)
{
    __shared__ int s[256];
    int t = threadIdx.x;
    int base = blockIdx.x * 1024 + t * 4;
    int4 v = {0, 0, 0, 0};
    if (base + 3 < n) {
        v = *(const int4*)&counts[base];
    } else {
        if (base + 0 < n) v.x = counts[base + 0];
        if (base + 1 < n) v.y = counts[base + 1];
        if (base + 2 < n) v.z = counts[base + 2];
        if (base + 3 < n) v.w = counts[base + 3];
    }
    int tsum = v.x + v.y + v.z + v.w;
    s[t] = tsum;
    __syncthreads();
#pragma unroll
    for (int off = 1; off < 256; off <<= 1) {
        int val = (t >= off) ? s[t - off] : 0;
        __syncthreads();
        s[t] += val;
        __syncthreads();
    }
    if (t == 255) blockSums[blockIdx.x] = s[255];
    int e0 = s[t] - tsum;
    int e1 = e0 + v.x;
    int e2 = e1 + v.y;
    int e3 = e2 + v.z;
    if (base + 0 < n) excl[base + 0] = e0;
    if (base + 1 < n) excl[base + 1] = e1;
    if (base + 2 < n) excl[base + 2] = e2;
    if (base + 3 < n) excl[base + 3] = e3;
}

// phase2: single block exclusive-scans blockSums (nb <= 256)
__global__ __launch_bounds__(256) void scan_phase2(int* blockSums, int nb)
{
    __shared__ int s[256];
    int t = threadIdx.x;
    int v = (t < nb) ? blockSums[t] : 0;
    s[t] = v;
    __syncthreads();
#pragma unroll
    for (int off = 1; off < 256; off <<= 1) {
        int val = (t >= off) ? s[t - off] : 0;
        __syncthreads();
        s[t] += val;
        __syncthreads();
    }
    if (t < nb) blockSums[t] = s[t] - v;
}

// phase3: add block offsets; init cursor
__global__ __launch_bounds__(256) void scan_phase3(
    int* __restrict__ offsets, const int* __restrict__ blockSums,
    int* __restrict__ cursor, int n)
{
    int i = blockIdx.x * 256 + threadIdx.x;
    if (i >= n) return;
    int o = offsets[i] + blockSums[i >> 10];
    offsets[i] = o;
    cursor[i]  = o;
}

// bucket scatter: edata[pos] = (col, val-bits), pos allocated via cursor
__global__ __launch_bounds__(256) void scatter_kernel(
    const int* __restrict__ row, const int* __restrict__ col,
    const float* __restrict__ val, int* __restrict__ cursor,
    uint2* __restrict__ edata, int E)
{
    int e = blockIdx.x * 256 + threadIdx.x;
    if (e >= E) return;
    int r = row[e];
    int pos = atomicAdd(&cursor[r], 1);
    uint2 d;
    d.x = (unsigned)col[e];
    d.y = __float_as_uint(val[e]);
    edata[pos] = d;
}

// pull SpMM: one wave per row, lane = emb dim; writes bf16 directly
__global__ __launch_bounds__(256) void pull_kernel(
    const int* __restrict__ offsets, const int* __restrict__ counts,
    const uint2* __restrict__ edata, const float* __restrict__ emb,
    unsigned short* __restrict__ xb, int Nn)
{
    int gid  = blockIdx.x * 256 + threadIdx.x;
    int r    = gid >> 6;
    int lane = gid & 63;
    if (r >= Nn) return;
    int beg = offsets[r];
    int cnt = counts[r];
    float acc = 0.f;
    for (int i = 0; i < cnt; ++i) {
        uint2 ed = edata[beg + i];
        acc += __uint_as_float(ed.y) * emb[(size_t)ed.x * EMB + lane];
    }
    xb[(size_t)r * EMB + lane] = f2bf(acc);
}

// ---------------------------------------------------------------------------
// fallback scatter SpMM (fp32 atomics) — only if ws too small for CSR path
// ---------------------------------------------------------------------------
__global__ __launch_bounds__(256) void spmm_kernel(
    const int* __restrict__ row, const int* __restrict__ col,
    const float* __restrict__ val, const float* __restrict__ emb,
    float* __restrict__ x, int E)
{
    int gid  = blockIdx.x * blockDim.x + threadIdx.x;
    int e    = gid >> 6;
    int lane = gid & 63;
    if (e >= E) return;
    unsafeAtomicAdd(&x[(size_t)row[e] * EMB + lane],
                    val[e] * emb[(size_t)col[e] * EMB + lane]);
}

// ---------------------------------------------------------------------------
// transpose + convert: in fp32 [K][256] -> out bf16 [256][K]
// ---------------------------------------------------------------------------
__global__ __launch_bounds__(256) void transpose_cvt(
    const float* __restrict__ in, unsigned short* __restrict__ out, int K)
{
    int i = blockIdx.x * 256 + threadIdx.x;
    if (i >= K * 256) return;
    int k = i >> 8;
    int n = i & 255;
    out[(size_t)n * K + k] = f2bf(in[i]);
}

// ---------------------------------------------------------------------------
// MFMA GEMM: C[M x 256] = relu?(A[M x K] @ B[K x 256]),  B given as Bt[256][K]
// block = 256 threads (4 waves), BM=64, BN=256, BK=64
// In-place safe (A may alias C): blocks only touch their own 64 rows; all
// A-reads complete before the pre-compute __syncthreads; stores in epilogue.
// ---------------------------------------------------------------------------
template<int K, bool RELU, bool OUT_BF16>
__global__ __launch_bounds__(256) void gemm_mfma(
    const unsigned short* A, const unsigned short* __restrict__ Bt,
    void* Cv, int M)
{
    constexpr int BK  = 64;
    constexpr int LDA = BK + 8;                // 72 bf16 = 144B padded stride
    __shared__ unsigned short As[64 * LDA];
    __shared__ unsigned short Bs[256 * LDA];

    const int t    = threadIdx.x;
    const int lane = t & 63;
    const int w    = t >> 6;                   // wave 0..3
    const int lr   = lane & 15;                // row (A) / col (B) within tile
    const int kg   = lane >> 4;                // k-group 0..3
    const int row0 = blockIdx.x * 64;

    f32x4 acc[4][4] = {};                      // [m-tile][n-tile]

    for (int k0 = 0; k0 < K; k0 += BK) {
        __syncthreads();
#pragma unroll
        for (int c = 0; c < 2; ++c) {
            int chunk = t + c * 256;
            int r  = chunk >> 3;
            int ko = (chunk & 7) * 8;
            int gr = row0 + r;
            const unsigned short* src = A + (size_t)(gr < M ? gr : 0) * K + k0 + ko;
            *(short8_t*)&As[r * LDA + ko] = *(const short8_t*)src;
        }
#pragma unroll
        for (int c = 0; c < 8; ++c) {
            int chunk = t + c * 256;
            int n  = chunk >> 3;
            int ko = (chunk & 7) * 8;
            *(short8_t*)&Bs[n * LDA + ko] =
                *(const short8_t*)(Bt + (size_t)n * K + k0 + ko);
        }
        __syncthreads();

#pragma unroll
        for (int ks = 0; ks < BK; ks += 32) {
            short8_t a[4], b[4];
#pragma unroll
            for (int m = 0; m < 4; ++m)
                a[m] = *(const short8_t*)&As[(m * 16 + lr) * LDA + ks + kg * 8];
#pragma unroll
            for (int n = 0; n < 4; ++n)
                b[n] = *(const short8_t*)&Bs[(w * 64 + n * 16 + lr) * LDA + ks + kg * 8];
#pragma unroll
            for (int m = 0; m < 4; ++m)
#pragma unroll
                for (int n = 0; n < 4; ++n)
                    acc[m][n] = __builtin_amdgcn_mfma_f32_16x16x32_bf16(
                        a[m], b[n], acc[m][n], 0, 0, 0);
        }
    }

    // epilogue: D mapping col = lane&15, row = (lane>>4)*4 + reg
#pragma unroll
    for (int m = 0; m < 4; ++m) {
#pragma unroll
        for (int r = 0; r < 4; ++r) {
            int gr = row0 + m * 16 + kg * 4 + r;
            if (gr < M) {
#pragma unroll
                for (int n = 0; n < 4; ++n) {
                    float v = acc[m][n][r];
                    if (RELU) v = fmaxf(v, 0.f);
                    int gc = w * 64 + n * 16 + lr;
                    if (OUT_BF16)
                        ((unsigned short*)Cv)[(size_t)gr * 256 + gc] = f2bf(v);
                    else
                        ((float*)Cv)[(size_t)gr * 256 + gc] = v;
                }
            }
        }
    }
}

// ---------------------------------------------------------------------------
// fp32 fallback GEMM — used only if ws_size is too small
// ---------------------------------------------------------------------------
template<int K, bool RELU>
__global__ __launch_bounds__(256) void gemm_f32(
    const float* A, const float* __restrict__ B, float* C, int M)
{
    __shared__ float As[64][17];
    __shared__ float Bs[16][256];

    const int t    = threadIdx.x;
    const int tn   = t & 15;
    const int row0 = blockIdx.x * 64;
    const int sk = t & 15;
    const int sm = (t >> 4) * 4;

    float acc[4][16];
#pragma unroll
    for (int i = 0; i < 4; ++i)
#pragma unroll
        for (int j = 0; j < 16; ++j) acc[i][j] = 0.f;

    const int mB = ((t & 63) >> 4) * 4;
    const int wq = t >> 6;
    const int myM = (wq * 16) + mB;

    for (int k0 = 0; k0 < K; k0 += 16) {
        __syncthreads();
#pragma unroll
        for (int i = 0; i < 4; ++i) {
            int m  = sm + i;
            int gr = row0 + m;
            As[m][sk] = (gr < M) ? A[(size_t)gr * K + k0 + sk] : 0.f;
        }
#pragma unroll
        for (int r = 0; r < 16; ++r)
            Bs[r][t] = B[(size_t)(k0 + r) * 256 + t];
        __syncthreads();

#pragma unroll
        for (int kk = 0; kk < 16; ++kk) {
            float a0 = As[myM + 0][kk];
            float a1 = As[myM + 1][kk];
            float a2 = As[myM + 2][kk];
            float a3 = As[myM + 3][kk];
            float4 b[4];
#pragma unroll
            for (int j = 0; j < 4; ++j)
                b[j] = *(const float4*)&Bs[kk][tn * 4 + j * 64];
#pragma unroll
            for (int j = 0; j < 4; ++j) {
                acc[0][j*4+0] += a0 * b[j].x;  acc[0][j*4+1] += a0 * b[j].y;
                acc[0][j*4+2] += a0 * b[j].z;  acc[0][j*4+3] += a0 * b[j].w;
                acc[1][j*4+0] += a1 * b[j].x;  acc[1][j*4+1] += a1 * b[j].y;
                acc[1][j*4+2] += a1 * b[j].z;  acc[1][j*4+3] += a1 * b[j].w;
                acc[2][j*4+0] += a2 * b[j].x;  acc[2][j*4+1] += a2 * b[j].y;
                acc[2][j*4+2] += a2 * b[j].z;  acc[2][j*4+3] += a2 * b[j].w;
                acc[3][j*4+0] += a3 * b[j].x;  acc[3][j*4+1] += a3 * b[j].y;
                acc[3][j*4+2] += a3 * b[j].z;  acc[3][j*4+3] += a3 * b[j].w;
            }
        }
    }

#pragma unroll
    for (int i = 0; i < 4; ++i) {
        int gr = row0 + myM + i;
        if (gr < M) {
#pragma unroll
            for (int j = 0; j < 4; ++j) {
                float4 o;
                o.x = acc[i][j*4+0]; o.y = acc[i][j*4+1];
                o.z = acc[i][j*4+2]; o.w = acc[i][j*4+3];
                if (RELU) {
                    o.x = fmaxf(o.x, 0.f); o.y = fmaxf(o.y, 0.f);
                    o.z = fmaxf(o.z, 0.f); o.w = fmaxf(o.w, 0.f);
                }
                *(float4*)&C[(size_t)gr * 256 + tn * 4 + j * 64] = o;
            }
        }
    }
}

extern "C" void kernel_launch(void* const* d_in, const int* in_sizes, int n_in,
                              void* d_out, int out_size, void* d_ws, size_t ws_size,
                              hipStream_t stream)
{
    const int*   row = (const int*)d_in[0];
    const int*   col = (const int*)d_in[1];
    const float* val = (const float*)d_in[2];
    const float* emb = (const float*)d_in[3];
    const float* W0  = (const float*)d_in[4];
    const float* W1  = (const float*)d_in[5];
    const float* W2  = (const float*)d_in[6];
    float* out = (float*)d_out;

    const int E = in_sizes[0];
    const int M = in_sizes[3] / EMB;   // num nodes

    char* ws = (char*)d_ws;

    // ---- ws layout (256B-aligned regions) ----
    size_t off = 0;
    auto alloc = [&](size_t bytes) { size_t o = off; off = (off + bytes + 255) & ~(size_t)255; return o; };
    const size_t off_counts = alloc((size_t)M * 4);
    const size_t off_offs   = alloc((size_t)M * 4);
    const size_t off_cursor = alloc((size_t)M * 4);
    const size_t off_bsums  = alloc(1024);
    const size_t off_edata  = alloc((size_t)E * 8);
    const size_t off_xb     = alloc((size_t)M * EMB * 2);
    const size_t off_h      = alloc((size_t)M * HID * 2);
    const size_t off_w0     = alloc((size_t)EMB * HID * 2);
    const size_t off_w1     = alloc((size_t)HID * HID * 2);
    const size_t off_w2     = alloc((size_t)HID * HID * 2);
    const size_t need       = off;

    int gblocks = (M + 63) / 64;

    if (ws_size >= need) {
        int*   counts = (int*)(ws + off_counts);
        int*   offs   = (int*)(ws + off_offs);
        int*   cursor = (int*)(ws + off_cursor);
        int*   bsums  = (int*)(ws + off_bsums);
        uint2* edata  = (uint2*)(ws + off_edata);
        unsigned short* xb  = (unsigned short*)(ws + off_xb);
        unsigned short* h   = (unsigned short*)(ws + off_h);
        unsigned short* W0t = (unsigned short*)(ws + off_w0);
        unsigned short* W1t = (unsigned short*)(ws + off_w1);
        unsigned short* W2t = (unsigned short*)(ws + off_w2);

        // CSR build
        (void)hipMemsetAsync(counts, 0, (size_t)M * 4, stream);
        hist_kernel<<<(E + 255) / 256, 256, 0, stream>>>(row, counts, E);
        int nb = (M + 1023) / 1024;              // 98 for M=100k (<=256)
        scan_phase1<<<nb, 256, 0, stream>>>(counts, offs, bsums, M);
        scan_phase2<<<1, 256, 0, stream>>>(bsums, nb);
        scan_phase3<<<(M + 255) / 256, 256, 0, stream>>>(offs, bsums, cursor, M);
        scatter_kernel<<<(E + 255) / 256, 256, 0, stream>>>(row, col, val, cursor, edata, E);

        // weight prep (tiny)
        transpose_cvt<<<(EMB * HID + 255) / 256, 256, 0, stream>>>(W0, W0t, EMB);
        transpose_cvt<<<(HID * HID + 255) / 256, 256, 0, stream>>>(W1, W1t, HID);
        transpose_cvt<<<(HID * HID + 255) / 256, 256, 0, stream>>>(W2, W2t, HID);

        // pull SpMM -> xb (bf16), covers all rows (zero-degree rows -> 0)
        pull_kernel<<<(M * 64 + 255) / 256, 256, 0, stream>>>(offs, counts, edata, emb, xb, M);

        // MLP
        gemm_mfma<EMB, true,  true ><<<gblocks, 256, 0, stream>>>(xb, W0t, h, M);
        gemm_mfma<HID, true,  true ><<<gblocks, 256, 0, stream>>>(h,  W1t, h, M);
        gemm_mfma<HID, false, false><<<gblocks, 256, 0, stream>>>(h,  W2t, out, M);
    } else {
        // fp32 fallback (ws too small): atomic scatter SpMM + fp32 GEMMs
        float* x = (float*)ws;
        (void)hipMemsetAsync(x, 0, (size_t)M * EMB * sizeof(float), stream);
        spmm_kernel<<<(E + 3) / 4, 256, 0, stream>>>(row, col, val, emb, x, E);
        gemm_f32<EMB, true ><<<gblocks, 256, 0, stream>>>(x,   W0, out, M);
        gemm_f32<HID, true ><<<gblocks, 256, 0, stream>>>(out, W1, out, M);
        gemm_f32<HID, false><<<gblocks, 256, 0, stream>>>(out, W2, out, M);
    }
}

// Round 5
// 232.007 us; speedup vs baseline: 2.6632x; 1.1358x over previous
//
#include <hip/hip_runtime.h>
#include <hip/hip_bf16.h>

#define EMB 64
#define HID 256

typedef __attribute__((ext_vector_type(8))) short short8_t;   // 8 bf16 = 4 VGPRs
typedef __attribute__((ext_vector_type(4))) float f32x4;

// fp32 -> bf16 bits, round-to-nearest-even (matches HW conversion)
__device__ __forceinline__ unsigned short f2bf(float f)
{
    union { float f; unsigned int u; } c; c.f = f;
    unsigned int u = c.u;
    u += 0x7fffu + ((u >> 16) & 1u);
    return (unsigned short)(u >> 16);
}
__device__ __forceinline__ float bf2f(unsigned short b)
{
    union { unsigned int u; float f; } c; c.u = ((unsigned int)b) << 16;
    return c.f;
}

// ---------------------------------------------------------------------------
// CSR build: histogram -> exclusive scan -> bucket scatter
// ---------------------------------------------------------------------------
__global__ __launch_bounds__(256) void hist_kernel(
    const int* __restrict__ row, int* __restrict__ counts, int E)
{
    int base = (blockIdx.x * 256 + threadIdx.x) * 4;
    if (base + 3 < E) {
        int4 r4 = *(const int4*)&row[base];
        atomicAdd(&counts[r4.x], 1);
        atomicAdd(&counts[r4.y], 1);
        atomicAdd(&counts[r4.z], 1);
        atomicAdd(&counts[r4.w], 1);
    } else {
        for (int i = base; i < E; ++i) atomicAdd(&counts[row[i]], 1);
    }
}

// phase1: per-block (1024 elems) exclusive scan; block total -> blockSums
__global__ __launch_bounds__(256) void scan_phase1(
    const int* __restrict__ counts, int* __restrict__ excl,
    int* __restrict__ blockSums, int n)
{
    __shared__ int s[256];
    int t = threadIdx.x;
    int base = blockIdx.x * 1024 + t * 4;
    int4 v = {0, 0, 0, 0};
    if (base + 3 < n) {
        v = *(const int4*)&counts[base];
    } else {
        if (base + 0 < n) v.x = counts[base + 0];
        if (base + 1 < n) v.y = counts[base + 1];
        if (base + 2 < n) v.z = counts[base + 2];
        if (base + 3 < n) v.w = counts[base + 3];
    }
    int tsum = v.x + v.y + v.z + v.w;
    s[t] = tsum;
    __syncthreads();
#pragma unroll
    for (int off = 1; off < 256; off <<= 1) {
        int val = (t >= off) ? s[t - off] : 0;
        __syncthreads();
        s[t] += val;
        __syncthreads();
    }
    if (t == 255) blockSums[blockIdx.x] = s[255];
    int e0 = s[t] - tsum;
    int e1 = e0 + v.x;
    int e2 = e1 + v.y;
    int e3 = e2 + v.z;
    if (base + 0 < n) excl[base + 0] = e0;
    if (base + 1 < n) excl[base + 1] = e1;
    if (base + 2 < n) excl[base + 2] = e2;
    if (base + 3 < n) excl[base + 3] = e3;
}

// phase2: single block exclusive-scans blockSums (nb <= 256)
__global__ __launch_bounds__(256) void scan_phase2(int* blockSums, int nb)
{
    __shared__ int s[256];
    int t = threadIdx.x;
    int v = (t < nb) ? blockSums[t] : 0;
    s[t] = v;
    __syncthreads();
#pragma unroll
    for (int off = 1; off < 256; off <<= 1) {
        int val = (t >= off) ? s[t - off] : 0;
        __syncthreads();
        s[t] += val;
        __syncthreads();
    }
    if (t < nb) blockSums[t] = s[t] - v;
}

// phase3: add block offsets; init cursor
__global__ __launch_bounds__(256) void scan_phase3(
    int* __restrict__ offsets, const int* __restrict__ blockSums,
    int* __restrict__ cursor, int n)
{
    int i = blockIdx.x * 256 + threadIdx.x;
    if (i >= n) return;
    int o = offsets[i] + blockSums[i >> 10];
    offsets[i] = o;
    cursor[i]  = o;
}

// bucket scatter: edata[pos] = (col, val-bits), pos allocated via cursor
__global__ __launch_bounds__(256) void scatter_kernel(
    const int* __restrict__ row, const int* __restrict__ col,
    const float* __restrict__ val, int* __restrict__ cursor,
    uint2* __restrict__ edata, int E)
{
    int e = blockIdx.x * 256 + threadIdx.x;
    if (e >= E) return;
    int r = row[e];
    int pos = atomicAdd(&cursor[r], 1);
    uint2 d;
    d.x = (unsigned)col[e];
    d.y = __float_as_uint(val[e]);
    edata[pos] = d;
}

// ---------------------------------------------------------------------------
// pull SpMM v2: one wave per row, lane = emb dim, 8-deep ILP, bf16 emb table
// ---------------------------------------------------------------------------
__global__ __launch_bounds__(256) void pull_kernel(
    const int* __restrict__ offsets, const int* __restrict__ counts,
    const uint2* __restrict__ edata, const unsigned short* __restrict__ embb,
    unsigned short* __restrict__ xb, int Nn)
{
    int r    = blockIdx.x * 4 + (threadIdx.x >> 6);
    int lane = threadIdx.x & 63;
    if (r >= Nn) return;
    int beg = offsets[r];
    int cnt = counts[r];
    float acc = 0.f;
    for (int i = 0; i < cnt; i += 8) {
        // 8 independent edge-record loads (wave-uniform -> broadcast)
        uint2 ed[8];
#pragma unroll
        for (int j = 0; j < 8; ++j) {
            int idx = i + j;
            idx = (idx < cnt) ? idx : (cnt - 1);
            ed[j] = edata[beg + idx];
        }
        // 8 independent gathers, then accumulate
        float g[8];
#pragma unroll
        for (int j = 0; j < 8; ++j)
            g[j] = bf2f(embb[(size_t)ed[j].x * EMB + lane]);
#pragma unroll
        for (int j = 0; j < 8; ++j) {
            float v = (i + j < cnt) ? __uint_as_float(ed[j].y) : 0.f;
            acc += v * g[j];
        }
    }
    xb[(size_t)r * EMB + lane] = f2bf(acc);
}

// ---------------------------------------------------------------------------
// fallback scatter SpMM (fp32 atomics) — only if ws too small for CSR path
// ---------------------------------------------------------------------------
__global__ __launch_bounds__(256) void spmm_kernel(
    const int* __restrict__ row, const int* __restrict__ col,
    const float* __restrict__ val, const float* __restrict__ emb,
    float* __restrict__ x, int E)
{
    int gid  = blockIdx.x * blockDim.x + threadIdx.x;
    int e    = gid >> 6;
    int lane = gid & 63;
    if (e >= E) return;
    unsafeAtomicAdd(&x[(size_t)row[e] * EMB + lane],
                    val[e] * emb[(size_t)col[e] * EMB + lane]);
}

// ---------------------------------------------------------------------------
// convert fp32 -> bf16, 4 elems/thread (n must be multiple of 4)
// ---------------------------------------------------------------------------
__global__ __launch_bounds__(256) void cvt_f32_bf16(
    const float* __restrict__ in, unsigned short* __restrict__ out, int n)
{
    int idx = (blockIdx.x * blockDim.x + threadIdx.x) * 4;
    if (idx >= n) return;
    float4 v = *(const float4*)&in[idx];
    ushort4 o;
    o.x = f2bf(v.x);
    o.y = f2bf(v.y);
    o.z = f2bf(v.z);
    o.w = f2bf(v.w);
    *(ushort4*)&out[idx] = o;
}

// ---------------------------------------------------------------------------
// transpose + convert: in fp32 [K][256] -> out bf16 [256][K]
// ---------------------------------------------------------------------------
__global__ __launch_bounds__(256) void transpose_cvt(
    const float* __restrict__ in, unsigned short* __restrict__ out, int K)
{
    int i = blockIdx.x * 256 + threadIdx.x;
    if (i >= K * 256) return;
    int k = i >> 8;
    int n = i & 255;
    out[(size_t)n * K + k] = f2bf(in[i]);
}

// ---------------------------------------------------------------------------
// MFMA GEMM: C[M x 256] = relu?(A[M x K] @ B[K x 256]),  B given as Bt[256][K]
// block = 256 threads (4 waves), BM=64, BN=256, BK=64
// In-place safe (A may alias C): blocks only touch their own 64 rows; all
// A-reads complete before the pre-compute __syncthreads; stores in epilogue.
// ---------------------------------------------------------------------------
template<int K, bool RELU, bool OUT_BF16>
__global__ __launch_bounds__(256) void gemm_mfma(
    const unsigned short* A, const unsigned short* __restrict__ Bt,
    void* Cv, int M)
{
    constexpr int BK  = 64;
    constexpr int LDA = BK + 8;                // 72 bf16 = 144B padded stride
    __shared__ unsigned short As[64 * LDA];
    __shared__ unsigned short Bs[256 * LDA];

    const int t    = threadIdx.x;
    const int lane = t & 63;
    const int w    = t >> 6;                   // wave 0..3
    const int lr   = lane & 15;                // row (A) / col (B) within tile
    const int kg   = lane >> 4;                // k-group 0..3
    const int row0 = blockIdx.x * 64;

    f32x4 acc[4][4] = {};                      // [m-tile][n-tile]

    for (int k0 = 0; k0 < K; k0 += BK) {
        __syncthreads();
#pragma unroll
        for (int c = 0; c < 2; ++c) {
            int chunk = t + c * 256;
            int r  = chunk >> 3;
            int ko = (chunk & 7) * 8;
            int gr = row0 + r;
            const unsigned short* src = A + (size_t)(gr < M ? gr : 0) * K + k0 + ko;
            *(short8_t*)&As[r * LDA + ko] = *(const short8_t*)src;
        }
#pragma unroll
        for (int c = 0; c < 8; ++c) {
            int chunk = t + c * 256;
            int n  = chunk >> 3;
            int ko = (chunk & 7) * 8;
            *(short8_t*)&Bs[n * LDA + ko] =
                *(const short8_t*)(Bt + (size_t)n * K + k0 + ko);
        }
        __syncthreads();

#pragma unroll
        for (int ks = 0; ks < BK; ks += 32) {
            short8_t a[4], b[4];
#pragma unroll
            for (int m = 0; m < 4; ++m)
                a[m] = *(const short8_t*)&As[(m * 16 + lr) * LDA + ks + kg * 8];
#pragma unroll
            for (int n = 0; n < 4; ++n)
                b[n] = *(const short8_t*)&Bs[(w * 64 + n * 16 + lr) * LDA + ks + kg * 8];
#pragma unroll
            for (int m = 0; m < 4; ++m)
#pragma unroll
                for (int n = 0; n < 4; ++n)
                    acc[m][n] = __builtin_amdgcn_mfma_f32_16x16x32_bf16(
                        a[m], b[n], acc[m][n], 0, 0, 0);
        }
    }

    // epilogue: D mapping col = lane&15, row = (lane>>4)*4 + reg
#pragma unroll
    for (int m = 0; m < 4; ++m) {
#pragma unroll
        for (int r = 0; r < 4; ++r) {
            int gr = row0 + m * 16 + kg * 4 + r;
            if (gr < M) {
#pragma unroll
                for (int n = 0; n < 4; ++n) {
                    float v = acc[m][n][r];
                    if (RELU) v = fmaxf(v, 0.f);
                    int gc = w * 64 + n * 16 + lr;
                    if (OUT_BF16)
                        ((unsigned short*)Cv)[(size_t)gr * 256 + gc] = f2bf(v);
                    else
                        ((float*)Cv)[(size_t)gr * 256 + gc] = v;
                }
            }
        }
    }
}

// ---------------------------------------------------------------------------
// fp32 fallback GEMM — used only if ws_size is too small
// ---------------------------------------------------------------------------
template<int K, bool RELU>
__global__ __launch_bounds__(256) void gemm_f32(
    const float* A, const float* __restrict__ B, float* C, int M)
{
    __shared__ float As[64][17];
    __shared__ float Bs[16][256];

    const int t    = threadIdx.x;
    const int tn   = t & 15;
    const int row0 = blockIdx.x * 64;
    const int sk = t & 15;
    const int sm = (t >> 4) * 4;

    float acc[4][16];
#pragma unroll
    for (int i = 0; i < 4; ++i)
#pragma unroll
        for (int j = 0; j < 16; ++j) acc[i][j] = 0.f;

    const int mB = ((t & 63) >> 4) * 4;
    const int wq = t >> 6;
    const int myM = (wq * 16) + mB;

    for (int k0 = 0; k0 < K; k0 += 16) {
        __syncthreads();
#pragma unroll
        for (int i = 0; i < 4; ++i) {
            int m  = sm + i;
            int gr = row0 + m;
            As[m][sk] = (gr < M) ? A[(size_t)gr * K + k0 + sk] : 0.f;
        }
#pragma unroll
        for (int r = 0; r < 16; ++r)
            Bs[r][t] = B[(size_t)(k0 + r) * 256 + t];
        __syncthreads();

#pragma unroll
        for (int kk = 0; kk < 16; ++kk) {
            float a0 = As[myM + 0][kk];
            float a1 = As[myM + 1][kk];
            float a2 = As[myM + 2][kk];
            float a3 = As[myM + 3][kk];
            float4 b[4];
#pragma unroll
            for (int j = 0; j < 4; ++j)
                b[j] = *(const float4*)&Bs[kk][tn * 4 + j * 64];
#pragma unroll
            for (int j = 0; j < 4; ++j) {
                acc[0][j*4+0] += a0 * b[j].x;  acc[0][j*4+1] += a0 * b[j].y;
                acc[0][j*4+2] += a0 * b[j].z;  acc[0][j*4+3] += a0 * b[j].w;
                acc[1][j*4+0] += a1 * b[j].x;  acc[1][j*4+1] += a1 * b[j].y;
                acc[1][j*4+2] += a1 * b[j].z;  acc[1][j*4+3] += a1 * b[j].w;
                acc[2][j*4+0] += a2 * b[j].x;  acc[2][j*4+1] += a2 * b[j].y;
                acc[2][j*4+2] += a2 * b[j].z;  acc[2][j*4+3] += a2 * b[j].w;
                acc[3][j*4+0] += a3 * b[j].x;  acc[3][j*4+1] += a3 * b[j].y;
                acc[3][j*4+2] += a3 * b[j].z;  acc[3][j*4+3] += a3 * b[j].w;
            }
        }
    }

#pragma unroll
    for (int i = 0; i < 4; ++i) {
        int gr = row0 + myM + i;
        if (gr < M) {
#pragma unroll
            for (int j = 0; j < 4; ++j) {
                float4 o;
                o.x = acc[i][j*4+0]; o.y = acc[i][j*4+1];
                o.z = acc[i][j*4+2]; o.w = acc[i][j*4+3];
                if (RELU) {
                    o.x = fmaxf(o.x, 0.f); o.y = fmaxf(o.y, 0.f);
                    o.z = fmaxf(o.z, 0.f); o.w = fmaxf(o.w, 0.f);
                }
                *(float4*)&C[(size_t)gr * 256 + tn * 4 + j * 64] = o;
            }
        }
    }
}

extern "C" void kernel_launch(void* const* d_in, const int* in_sizes, int n_in,
                              void* d_out, int out_size, void* d_ws, size_t ws_size,
                              hipStream_t stream)
{
    const int*   row = (const int*)d_in[0];
    const int*   col = (const int*)d_in[1];
    const float* val = (const float*)d_in[2];
    const float* emb = (const float*)d_in[3];
    const float* W0  = (const float*)d_in[4];
    const float* W1  = (const float*)d_in[5];
    const float* W2  = (const float*)d_in[6];
    float* out = (float*)d_out;

    const int E = in_sizes[0];
    const int M = in_sizes[3] / EMB;   // num nodes

    char* ws = (char*)d_ws;

    // ---- ws layout (256B-aligned regions) ----
    size_t off = 0;
    auto alloc = [&](size_t bytes) { size_t o = off; off = (off + bytes + 255) & ~(size_t)255; return o; };
    const size_t off_counts = alloc((size_t)M * 4);
    const size_t off_offs   = alloc((size_t)M * 4);
    const size_t off_cursor = alloc((size_t)M * 4);
    const size_t off_bsums  = alloc(1024);
    const size_t off_edata  = alloc((size_t)E * 8);
    const size_t off_embb   = alloc((size_t)M * EMB * 2);
    const size_t off_xb     = alloc((size_t)M * EMB * 2);
    const size_t off_h      = alloc((size_t)M * HID * 2);
    const size_t off_w0     = alloc((size_t)EMB * HID * 2);
    const size_t off_w1     = alloc((size_t)HID * HID * 2);
    const size_t off_w2     = alloc((size_t)HID * HID * 2);
    const size_t need       = off;

    int gblocks = (M + 63) / 64;

    if (ws_size >= need) {
        int*   counts = (int*)(ws + off_counts);
        int*   offs   = (int*)(ws + off_offs);
        int*   cursor = (int*)(ws + off_cursor);
        int*   bsums  = (int*)(ws + off_bsums);
        uint2* edata  = (uint2*)(ws + off_edata);
        unsigned short* embb = (unsigned short*)(ws + off_embb);
        unsigned short* xb  = (unsigned short*)(ws + off_xb);
        unsigned short* h   = (unsigned short*)(ws + off_h);
        unsigned short* W0t = (unsigned short*)(ws + off_w0);
        unsigned short* W1t = (unsigned short*)(ws + off_w1);
        unsigned short* W2t = (unsigned short*)(ws + off_w2);

        // CSR build
        (void)hipMemsetAsync(counts, 0, (size_t)M * 4, stream);
        hist_kernel<<<(E / 4 + 255) / 256, 256, 0, stream>>>(row, counts, E);
        int nb = (M + 1023) / 1024;              // 98 for M=100k (<=256)
        scan_phase1<<<nb, 256, 0, stream>>>(counts, offs, bsums, M);
        scan_phase2<<<1, 256, 0, stream>>>(bsums, nb);
        scan_phase3<<<(M + 255) / 256, 256, 0, stream>>>(offs, bsums, cursor, M);
        scatter_kernel<<<(E + 255) / 256, 256, 0, stream>>>(row, col, val, cursor, edata, E);

        // emb -> bf16 table; weight prep (tiny)
        cvt_f32_bf16<<<((M * EMB) / 4 + 255) / 256, 256, 0, stream>>>(emb, embb, M * EMB);
        transpose_cvt<<<(EMB * HID + 255) / 256, 256, 0, stream>>>(W0, W0t, EMB);
        transpose_cvt<<<(HID * HID + 255) / 256, 256, 0, stream>>>(W1, W1t, HID);
        transpose_cvt<<<(HID * HID + 255) / 256, 256, 0, stream>>>(W2, W2t, HID);

        // pull SpMM -> xb (bf16), covers all rows (zero-degree rows -> 0)
        pull_kernel<<<(M + 3) / 4, 256, 0, stream>>>(offs, counts, edata, embb, xb, M);

        // MLP
        gemm_mfma<EMB, true,  true ><<<gblocks, 256, 0, stream>>>(xb, W0t, h, M);
        gemm_mfma<HID, true,  true ><<<gblocks, 256, 0, stream>>>(h,  W1t, h, M);
        gemm_mfma<HID, false, false><<<gblocks, 256, 0, stream>>>(h,  W2t, out, M);
    } else {
        // fp32 fallback (ws too small): atomic scatter SpMM + fp32 GEMMs
        float* x = (float*)ws;
        (void)hipMemsetAsync(x, 0, (size_t)M * EMB * sizeof(float), stream);
        spmm_kernel<<<(E + 3) / 4, 256, 0, stream>>>(row, col, val, emb, x, E);
        gemm_f32<EMB, true ><<<gblocks, 256, 0, stream>>>(x,   W0, out, M);
        gemm_f32<HID, true ><<<gblocks, 256, 0, stream>>>(out, W1, out, M);
        gemm_f32<HID, false><<<gblocks, 256, 0, stream>>>(out, W2, out, M);
    }
}

// Round 6
// 221.121 us; speedup vs baseline: 2.7943x; 1.0492x over previous
//
#include <hip/hip_runtime.h>
#include <hip/hip_bf16.h>

#define EMB 64
#define HID 256

typedef __attribute__((ext_vector_type(8))) short short8_t;   // 8 bf16 = 4 VGPRs
typedef __attribute__((ext_vector_type(4))) float f32x4;

// fp32 -> bf16 bits, round-to-nearest-even (matches HW conversion)
__device__ __forceinline__ unsigned short f2bf(float f)
{
    union { float f; unsigned int u; } c; c.f = f;
    unsigned int u = c.u;
    u += 0x7fffu + ((u >> 16) & 1u);
    return (unsigned short)(u >> 16);
}
__device__ __forceinline__ float bf2f(unsigned short b)
{
    union { unsigned int u; float f; } c; c.u = ((unsigned int)b) << 16;
    return c.f;
}

// ---------------------------------------------------------------------------
// prep: block-range fused {zero counts | emb->bf16 | W0/W1/W2 transpose+cvt}
// grid = zb + cb + 64 + 256 + 256 blocks of 256 threads
// ---------------------------------------------------------------------------
__global__ __launch_bounds__(256) void prep_kernel(
    const float* __restrict__ emb, const float* __restrict__ W0,
    const float* __restrict__ W1, const float* __restrict__ W2,
    int* __restrict__ counts, unsigned short* __restrict__ embb,
    unsigned short* __restrict__ W0t, unsigned short* __restrict__ W1t,
    unsigned short* __restrict__ W2t, int M, int zb, int cb)
{
    int b = blockIdx.x;
    if (b < zb) {                              // zero counts[M]
        int idx = (b * 256 + threadIdx.x) * 4;
        if (idx + 3 < M) {
            int4 z; z.x = 0; z.y = 0; z.z = 0; z.w = 0;
            *(int4*)&counts[idx] = z;
        } else {
            for (int i = idx; i < M; ++i) counts[i] = 0;
        }
        return;
    }
    b -= zb;
    if (b < cb) {                              // emb fp32 -> bf16
        int idx = (b * 256 + threadIdx.x) * 4;
        if (idx + 3 < M * EMB) {
            float4 v = *(const float4*)&emb[idx];
            ushort4 o;
            o.x = f2bf(v.x); o.y = f2bf(v.y); o.z = f2bf(v.z); o.w = f2bf(v.w);
            *(ushort4*)&embb[idx] = o;
        }
        return;
    }
    b -= cb;
    if (b < EMB) {                             // W0 [64][256] -> W0t [256][64]
        int i = b * 256 + threadIdx.x;
        int k = i >> 8, n = i & 255;
        W0t[n * EMB + k] = f2bf(W0[i]);
        return;
    }
    b -= EMB;
    if (b < HID) {                             // W1 [256][256] -> W1t
        int i = b * 256 + threadIdx.x;
        int k = i >> 8, n = i & 255;
        W1t[n * HID + k] = f2bf(W1[i]);
        return;
    }
    b -= HID;
    {                                          // W2 [256][256] -> W2t
        int i = b * 256 + threadIdx.x;
        int k = i >> 8, n = i & 255;
        W2t[n * HID + k] = f2bf(W2[i]);
    }
}

// ---------------------------------------------------------------------------
// CSR build: histogram -> exclusive scan -> bucket scatter
// ---------------------------------------------------------------------------
__global__ __launch_bounds__(256) void hist_kernel(
    const int* __restrict__ row, int* __restrict__ counts, int E)
{
    int base = (blockIdx.x * 256 + threadIdx.x) * 4;
    if (base + 3 < E) {
        int4 r4 = *(const int4*)&row[base];
        atomicAdd(&counts[r4.x], 1);
        atomicAdd(&counts[r4.y], 1);
        atomicAdd(&counts[r4.z], 1);
        atomicAdd(&counts[r4.w], 1);
    } else {
        for (int i = base; i < E; ++i) atomicAdd(&counts[row[i]], 1);
    }
}

// phase1: per-block (1024 elems) exclusive scan; block total -> blockSums
__global__ __launch_bounds__(256) void scan_phase1(
    const int* __restrict__ counts, int* __restrict__ excl,
    int* __restrict__ blockSums, int n)
{
    __shared__ int s[256];
    int t = threadIdx.x;
    int base = blockIdx.x * 1024 + t * 4;
    int4 v = {0, 0, 0, 0};
    if (base + 3 < n) {
        v = *(const int4*)&counts[base];
    } else {
        if (base + 0 < n) v.x = counts[base + 0];
        if (base + 1 < n) v.y = counts[base + 1];
        if (base + 2 < n) v.z = counts[base + 2];
        if (base + 3 < n) v.w = counts[base + 3];
    }
    int tsum = v.x + v.y + v.z + v.w;
    s[t] = tsum;
    __syncthreads();
#pragma unroll
    for (int off = 1; off < 256; off <<= 1) {
        int val = (t >= off) ? s[t - off] : 0;
        __syncthreads();
        s[t] += val;
        __syncthreads();
    }
    if (t == 255) blockSums[blockIdx.x] = s[255];
    int e0 = s[t] - tsum;
    int e1 = e0 + v.x;
    int e2 = e1 + v.y;
    int e3 = e2 + v.z;
    if (base + 0 < n) excl[base + 0] = e0;
    if (base + 1 < n) excl[base + 1] = e1;
    if (base + 2 < n) excl[base + 2] = e2;
    if (base + 3 < n) excl[base + 3] = e3;
}

// phase2: single block exclusive-scans blockSums (nb <= 256)
__global__ __launch_bounds__(256) void scan_phase2(int* blockSums, int nb)
{
    __shared__ int s[256];
    int t = threadIdx.x;
    int v = (t < nb) ? blockSums[t] : 0;
    s[t] = v;
    __syncthreads();
#pragma unroll
    for (int off = 1; off < 256; off <<= 1) {
        int val = (t >= off) ? s[t - off] : 0;
        __syncthreads();
        s[t] += val;
        __syncthreads();
    }
    if (t < nb) blockSums[t] = s[t] - v;
}

// phase3: add block offsets; init cursor
__global__ __launch_bounds__(256) void scan_phase3(
    int* __restrict__ offsets, const int* __restrict__ blockSums,
    int* __restrict__ cursor, int n)
{
    int i = blockIdx.x * 256 + threadIdx.x;
    if (i >= n) return;
    int o = offsets[i] + blockSums[i >> 10];
    offsets[i] = o;
    cursor[i]  = o;
}

// bucket scatter: edata[pos] = (col, val-bits), pos allocated via cursor
__global__ __launch_bounds__(256) void scatter_kernel(
    const int* __restrict__ row, const int* __restrict__ col,
    const float* __restrict__ val, int* __restrict__ cursor,
    uint2* __restrict__ edata, int E)
{
    int e = blockIdx.x * 256 + threadIdx.x;
    if (e >= E) return;
    int r = row[e];
    int pos = atomicAdd(&cursor[r], 1);
    uint2 d;
    d.x = (unsigned)col[e];
    d.y = __float_as_uint(val[e]);
    edata[pos] = d;
}

// ---------------------------------------------------------------------------
// pull SpMM: one wave per row, lane = emb dim, 8-deep ILP, bf16 emb table
// ---------------------------------------------------------------------------
__global__ __launch_bounds__(256) void pull_kernel(
    const int* __restrict__ offsets, const int* __restrict__ counts,
    const uint2* __restrict__ edata, const unsigned short* __restrict__ embb,
    unsigned short* __restrict__ xb, int Nn)
{
    int r    = blockIdx.x * 4 + (threadIdx.x >> 6);
    int lane = threadIdx.x & 63;
    if (r >= Nn) return;
    int beg = offsets[r];
    int cnt = counts[r];
    float acc = 0.f;
    for (int i = 0; i < cnt; i += 8) {
        uint2 ed[8];
#pragma unroll
        for (int j = 0; j < 8; ++j) {
            int idx = i + j;
            idx = (idx < cnt) ? idx : (cnt - 1);
            ed[j] = edata[beg + idx];
        }
        float g[8];
#pragma unroll
        for (int j = 0; j < 8; ++j)
            g[j] = bf2f(embb[(size_t)ed[j].x * EMB + lane]);
#pragma unroll
        for (int j = 0; j < 8; ++j) {
            float v = (i + j < cnt) ? __uint_as_float(ed[j].y) : 0.f;
            acc += v * g[j];
        }
    }
    xb[(size_t)r * EMB + lane] = f2bf(acc);
}

// ---------------------------------------------------------------------------
// fallback scatter SpMM (fp32 atomics) — only if ws too small for CSR path
// ---------------------------------------------------------------------------
__global__ __launch_bounds__(256) void spmm_kernel(
    const int* __restrict__ row, const int* __restrict__ col,
    const float* __restrict__ val, const float* __restrict__ emb,
    float* __restrict__ x, int E)
{
    int gid  = blockIdx.x * blockDim.x + threadIdx.x;
    int e    = gid >> 6;
    int lane = gid & 63;
    if (e >= E) return;
    unsafeAtomicAdd(&x[(size_t)row[e] * EMB + lane],
                    val[e] * emb[(size_t)col[e] * EMB + lane]);
}

// ---------------------------------------------------------------------------
// MFMA GEMM: C[M x 256] = relu?(A[M x K] @ B[K x 256]),  B given as Bt[256][K]
// block = 256 threads (4 waves), BM=64, BN=256, BK=64
// In-place safe (A may alias C): blocks only touch their own 64 rows; all
// A-reads complete before the pre-compute __syncthreads; stores in epilogue.
// ---------------------------------------------------------------------------
template<int K, bool RELU, bool OUT_BF16>
__global__ __launch_bounds__(256) void gemm_mfma(
    const unsigned short* A, const unsigned short* __restrict__ Bt,
    void* Cv, int M)
{
    constexpr int BK  = 64;
    constexpr int LDA = BK + 8;                // 72 bf16 = 144B padded stride
    __shared__ unsigned short As[64 * LDA];
    __shared__ unsigned short Bs[256 * LDA];

    const int t    = threadIdx.x;
    const int lane = t & 63;
    const int w    = t >> 6;                   // wave 0..3
    const int lr   = lane & 15;                // row (A) / col (B) within tile
    const int kg   = lane >> 4;                // k-group 0..3
    const int row0 = blockIdx.x * 64;

    f32x4 acc[4][4] = {};                      // [m-tile][n-tile]

    for (int k0 = 0; k0 < K; k0 += BK) {
        __syncthreads();
#pragma unroll
        for (int c = 0; c < 2; ++c) {
            int chunk = t + c * 256;
            int r  = chunk >> 3;
            int ko = (chunk & 7) * 8;
            int gr = row0 + r;
            const unsigned short* src = A + (size_t)(gr < M ? gr : 0) * K + k0 + ko;
            *(short8_t*)&As[r * LDA + ko] = *(const short8_t*)src;
        }
#pragma unroll
        for (int c = 0; c < 8; ++c) {
            int chunk = t + c * 256;
            int n  = chunk >> 3;
            int ko = (chunk & 7) * 8;
            *(short8_t*)&Bs[n * LDA + ko] =
                *(const short8_t*)(Bt + (size_t)n * K + k0 + ko);
        }
        __syncthreads();

#pragma unroll
        for (int ks = 0; ks < BK; ks += 32) {
            short8_t a[4], b[4];
#pragma unroll
            for (int m = 0; m < 4; ++m)
                a[m] = *(const short8_t*)&As[(m * 16 + lr) * LDA + ks + kg * 8];
#pragma unroll
            for (int n = 0; n < 4; ++n)
                b[n] = *(const short8_t*)&Bs[(w * 64 + n * 16 + lr) * LDA + ks + kg * 8];
#pragma unroll
            for (int m = 0; m < 4; ++m)
#pragma unroll
                for (int n = 0; n < 4; ++n)
                    acc[m][n] = __builtin_amdgcn_mfma_f32_16x16x32_bf16(
                        a[m], b[n], acc[m][n], 0, 0, 0);
        }
    }

    // epilogue: D mapping col = lane&15, row = (lane>>4)*4 + reg
#pragma unroll
    for (int m = 0; m < 4; ++m) {
#pragma unroll
        for (int r = 0; r < 4; ++r) {
            int gr = row0 + m * 16 + kg * 4 + r;
            if (gr < M) {
#pragma unroll
                for (int n = 0; n < 4; ++n) {
                    float v = acc[m][n][r];
                    if (RELU) v = fmaxf(v, 0.f);
                    int gc = w * 64 + n * 16 + lr;
                    if (OUT_BF16)
                        ((unsigned short*)Cv)[(size_t)gr * 256 + gc] = f2bf(v);
                    else
                        ((float*)Cv)[(size_t)gr * 256 + gc] = v;
                }
            }
        }
    }
}

// ---------------------------------------------------------------------------
// fp32 fallback GEMM — used only if ws_size is too small
// ---------------------------------------------------------------------------
template<int K, bool RELU>
__global__ __launch_bounds__(256) void gemm_f32(
    const float* A, const float* __restrict__ B, float* C, int M)
{
    __shared__ float As[64][17];
    __shared__ float Bs[16][256];

    const int t    = threadIdx.x;
    const int tn   = t & 15;
    const int row0 = blockIdx.x * 64;
    const int sk = t & 15;
    const int sm = (t >> 4) * 4;

    float acc[4][16];
#pragma unroll
    for (int i = 0; i < 4; ++i)
#pragma unroll
        for (int j = 0; j < 16; ++j) acc[i][j] = 0.f;

    const int mB = ((t & 63) >> 4) * 4;
    const int wq = t >> 6;
    const int myM = (wq * 16) + mB;

    for (int k0 = 0; k0 < K; k0 += 16) {
        __syncthreads();
#pragma unroll
        for (int i = 0; i < 4; ++i) {
            int m  = sm + i;
            int gr = row0 + m;
            As[m][sk] = (gr < M) ? A[(size_t)gr * K + k0 + sk] : 0.f;
        }
#pragma unroll
        for (int r = 0; r < 16; ++r)
            Bs[r][t] = B[(size_t)(k0 + r) * 256 + t];
        __syncthreads();

#pragma unroll
        for (int kk = 0; kk < 16; ++kk) {
            float a0 = As[myM + 0][kk];
            float a1 = As[myM + 1][kk];
            float a2 = As[myM + 2][kk];
            float a3 = As[myM + 3][kk];
            float4 b[4];
#pragma unroll
            for (int j = 0; j < 4; ++j)
                b[j] = *(const float4*)&Bs[kk][tn * 4 + j * 64];
#pragma unroll
            for (int j = 0; j < 4; ++j) {
                acc[0][j*4+0] += a0 * b[j].x;  acc[0][j*4+1] += a0 * b[j].y;
                acc[0][j*4+2] += a0 * b[j].z;  acc[0][j*4+3] += a0 * b[j].w;
                acc[1][j*4+0] += a1 * b[j].x;  acc[1][j*4+1] += a1 * b[j].y;
                acc[1][j*4+2] += a1 * b[j].z;  acc[1][j*4+3] += a1 * b[j].w;
                acc[2][j*4+0] += a2 * b[j].x;  acc[2][j*4+1] += a2 * b[j].y;
                acc[2][j*4+2] += a2 * b[j].z;  acc[2][j*4+3] += a2 * b[j].w;
                acc[3][j*4+0] += a3 * b[j].x;  acc[3][j*4+1] += a3 * b[j].y;
                acc[3][j*4+2] += a3 * b[j].z;  acc[3][j*4+3] += a3 * b[j].w;
            }
        }
    }

#pragma unroll
    for (int i = 0; i < 4; ++i) {
        int gr = row0 + myM + i;
        if (gr < M) {
#pragma unroll
            for (int j = 0; j < 4; ++j) {
                float4 o;
                o.x = acc[i][j*4+0]; o.y = acc[i][j*4+1];
                o.z = acc[i][j*4+2]; o.w = acc[i][j*4+3];
                if (RELU) {
                    o.x = fmaxf(o.x, 0.f); o.y = fmaxf(o.y, 0.f);
                    o.z = fmaxf(o.z, 0.f); o.w = fmaxf(o.w, 0.f);
                }
                *(float4*)&C[(size_t)gr * 256 + tn * 4 + j * 64] = o;
            }
        }
    }
}

extern "C" void kernel_launch(void* const* d_in, const int* in_sizes, int n_in,
                              void* d_out, int out_size, void* d_ws, size_t ws_size,
                              hipStream_t stream)
{
    const int*   row = (const int*)d_in[0];
    const int*   col = (const int*)d_in[1];
    const float* val = (const float*)d_in[2];
    const float* emb = (const float*)d_in[3];
    const float* W0  = (const float*)d_in[4];
    const float* W1  = (const float*)d_in[5];
    const float* W2  = (const float*)d_in[6];
    float* out = (float*)d_out;

    const int E = in_sizes[0];
    const int M = in_sizes[3] / EMB;   // num nodes

    char* ws = (char*)d_ws;

    // ---- ws layout (256B-aligned regions) ----
    size_t off = 0;
    auto alloc = [&](size_t bytes) { size_t o = off; off = (off + bytes + 255) & ~(size_t)255; return o; };
    const size_t off_counts = alloc((size_t)M * 4);
    const size_t off_offs   = alloc((size_t)M * 4);
    const size_t off_cursor = alloc((size_t)M * 4);
    const size_t off_bsums  = alloc(1024);
    const size_t off_edata  = alloc((size_t)E * 8);
    const size_t off_embb   = alloc((size_t)M * EMB * 2);
    const size_t off_xb     = alloc((size_t)M * EMB * 2);
    const size_t off_h      = alloc((size_t)M * HID * 2);
    const size_t off_w0     = alloc((size_t)EMB * HID * 2);
    const size_t off_w1     = alloc((size_t)HID * HID * 2);
    const size_t off_w2     = alloc((size_t)HID * HID * 2);
    const size_t need       = off;

    int gblocks = (M + 63) / 64;

    if (ws_size >= need) {
        int*   counts = (int*)(ws + off_counts);
        int*   offs   = (int*)(ws + off_offs);
        int*   cursor = (int*)(ws + off_cursor);
        int*   bsums  = (int*)(ws + off_bsums);
        uint2* edata  = (uint2*)(ws + off_edata);
        unsigned short* embb = (unsigned short*)(ws + off_embb);
        unsigned short* xb  = (unsigned short*)(ws + off_xb);
        unsigned short* h   = (unsigned short*)(ws + off_h);
        unsigned short* W0t = (unsigned short*)(ws + off_w0);
        unsigned short* W1t = (unsigned short*)(ws + off_w1);
        unsigned short* W2t = (unsigned short*)(ws + off_w2);

        // fused prep: zero counts + emb->bf16 + weight transpose/cvt
        int zb = (M / 4 + 255) / 256;
        int cb = ((M * EMB) / 4 + 255) / 256;
        int prep_blocks = zb + cb + EMB + HID + HID;
        prep_kernel<<<prep_blocks, 256, 0, stream>>>(
            emb, W0, W1, W2, counts, embb, W0t, W1t, W2t, M, zb, cb);

        // CSR build
        hist_kernel<<<(E / 4 + 255) / 256, 256, 0, stream>>>(row, counts, E);
        int nb = (M + 1023) / 1024;              // 98 for M=100k (<=256)
        scan_phase1<<<nb, 256, 0, stream>>>(counts, offs, bsums, M);
        scan_phase2<<<1, 256, 0, stream>>>(bsums, nb);
        scan_phase3<<<(M + 255) / 256, 256, 0, stream>>>(offs, bsums, cursor, M);
        scatter_kernel<<<(E + 255) / 256, 256, 0, stream>>>(row, col, val, cursor, edata, E);

        // pull SpMM -> xb (bf16), covers all rows (zero-degree rows -> 0)
        pull_kernel<<<(M + 3) / 4, 256, 0, stream>>>(offs, counts, edata, embb, xb, M);

        // MLP
        gemm_mfma<EMB, true,  true ><<<gblocks, 256, 0, stream>>>(xb, W0t, h, M);
        gemm_mfma<HID, true,  true ><<<gblocks, 256, 0, stream>>>(h,  W1t, h, M);
        gemm_mfma<HID, false, false><<<gblocks, 256, 0, stream>>>(h,  W2t, out, M);
    } else {
        // fp32 fallback (ws too small): atomic scatter SpMM + fp32 GEMMs
        float* x = (float*)ws;
        (void)hipMemsetAsync(x, 0, (size_t)M * EMB * sizeof(float), stream);
        spmm_kernel<<<(E + 3) / 4, 256, 0, stream>>>(row, col, val, emb, x, E);
        gemm_f32<EMB, true ><<<gblocks, 256, 0, stream>>>(x,   W0, out, M);
        gemm_f32<HID, true ><<<gblocks, 256, 0, stream>>>(out, W1, out, M);
        gemm_f32<HID, false><<<gblocks, 256, 0, stream>>>(out, W2, out, M);
    }
}

// Round 7
// 203.573 us; speedup vs baseline: 3.0352x; 1.0862x over previous
//
#include <hip/hip_runtime.h>
#include <hip/hip_bf16.h>

#define EMB 64
#define HID 256

typedef __attribute__((ext_vector_type(8))) short short8_t;   // 8 bf16 = 4 VGPRs
typedef __attribute__((ext_vector_type(4))) float f32x4;

// fp32 -> bf16 bits, round-to-nearest-even (matches HW conversion)
__device__ __forceinline__ unsigned short f2bf(float f)
{
    union { float f; unsigned int u; } c; c.f = f;
    unsigned int u = c.u;
    u += 0x7fffu + ((u >> 16) & 1u);
    return (unsigned short)(u >> 16);
}
__device__ __forceinline__ float bf2f(unsigned short b)
{
    union { unsigned int u; float f; } c; c.u = ((unsigned int)b) << 16;
    return c.f;
}

// ---------------------------------------------------------------------------
// prep: block-range fused {zero counts | emb->bf16 | W0/W1/W2 transpose+cvt}
// ---------------------------------------------------------------------------
__global__ __launch_bounds__(256) void prep_kernel(
    const float* __restrict__ emb, const float* __restrict__ W0,
    const float* __restrict__ W1, const float* __restrict__ W2,
    int* __restrict__ counts, unsigned short* __restrict__ embb,
    unsigned short* __restrict__ W0t, unsigned short* __restrict__ W1t,
    unsigned short* __restrict__ W2t, int M, int zb, int cb)
{
    int b = blockIdx.x;
    if (b < zb) {                              // zero counts[M]
        int idx = (b * 256 + threadIdx.x) * 4;
        if (idx + 3 < M) {
            int4 z; z.x = 0; z.y = 0; z.z = 0; z.w = 0;
            *(int4*)&counts[idx] = z;
        } else {
            for (int i = idx; i < M; ++i) counts[i] = 0;
        }
        return;
    }
    b -= zb;
    if (b < cb) {                              // emb fp32 -> bf16
        int idx = (b * 256 + threadIdx.x) * 4;
        if (idx + 3 < M * EMB) {
            float4 v = *(const float4*)&emb[idx];
            ushort4 o;
            o.x = f2bf(v.x); o.y = f2bf(v.y); o.z = f2bf(v.z); o.w = f2bf(v.w);
            *(ushort4*)&embb[idx] = o;
        }
        return;
    }
    b -= cb;
    if (b < EMB) {                             // W0 [64][256] -> W0t [256][64]
        int i = b * 256 + threadIdx.x;
        int k = i >> 8, n = i & 255;
        W0t[n * EMB + k] = f2bf(W0[i]);
        return;
    }
    b -= EMB;
    if (b < HID) {                             // W1 [256][256] -> W1t
        int i = b * 256 + threadIdx.x;
        int k = i >> 8, n = i & 255;
        W1t[n * HID + k] = f2bf(W1[i]);
        return;
    }
    b -= HID;
    {                                          // W2 [256][256] -> W2t
        int i = b * 256 + threadIdx.x;
        int k = i >> 8, n = i & 255;
        W2t[n * HID + k] = f2bf(W2[i]);
    }
}

// ---------------------------------------------------------------------------
// CSR build: histogram -> exclusive scan -> bucket scatter
// ---------------------------------------------------------------------------
__global__ __launch_bounds__(256) void hist_kernel(
    const int* __restrict__ row, int* __restrict__ counts, int E)
{
    int base = (blockIdx.x * 256 + threadIdx.x) * 4;
    if (base + 3 < E) {
        int4 r4 = *(const int4*)&row[base];
        atomicAdd(&counts[r4.x], 1);
        atomicAdd(&counts[r4.y], 1);
        atomicAdd(&counts[r4.z], 1);
        atomicAdd(&counts[r4.w], 1);
    } else {
        for (int i = base; i < E; ++i) atomicAdd(&counts[row[i]], 1);
    }
}

__global__ __launch_bounds__(256) void scan_phase1(
    const int* __restrict__ counts, int* __restrict__ excl,
    int* __restrict__ blockSums, int n)
{
    __shared__ int s[256];
    int t = threadIdx.x;
    int base = blockIdx.x * 1024 + t * 4;
    int4 v = {0, 0, 0, 0};
    if (base + 3 < n) {
        v = *(const int4*)&counts[base];
    } else {
        if (base + 0 < n) v.x = counts[base + 0];
        if (base + 1 < n) v.y = counts[base + 1];
        if (base + 2 < n) v.z = counts[base + 2];
        if (base + 3 < n) v.w = counts[base + 3];
    }
    int tsum = v.x + v.y + v.z + v.w;
    s[t] = tsum;
    __syncthreads();
#pragma unroll
    for (int off = 1; off < 256; off <<= 1) {
        int val = (t >= off) ? s[t - off] : 0;
        __syncthreads();
        s[t] += val;
        __syncthreads();
    }
    if (t == 255) blockSums[blockIdx.x] = s[255];
    int e0 = s[t] - tsum;
    int e1 = e0 + v.x;
    int e2 = e1 + v.y;
    int e3 = e2 + v.z;
    if (base + 0 < n) excl[base + 0] = e0;
    if (base + 1 < n) excl[base + 1] = e1;
    if (base + 2 < n) excl[base + 2] = e2;
    if (base + 3 < n) excl[base + 3] = e3;
}

__global__ __launch_bounds__(256) void scan_phase2(int* blockSums, int nb)
{
    __shared__ int s[256];
    int t = threadIdx.x;
    int v = (t < nb) ? blockSums[t] : 0;
    s[t] = v;
    __syncthreads();
#pragma unroll
    for (int off = 1; off < 256; off <<= 1) {
        int val = (t >= off) ? s[t - off] : 0;
        __syncthreads();
        s[t] += val;
        __syncthreads();
    }
    if (t < nb) blockSums[t] = s[t] - v;
}

__global__ __launch_bounds__(256) void scan_phase3(
    int* __restrict__ offsets, const int* __restrict__ blockSums,
    int* __restrict__ cursor, int n)
{
    int i = blockIdx.x * 256 + threadIdx.x;
    if (i >= n) return;
    int o = offsets[i] + blockSums[i >> 10];
    offsets[i] = o;
    cursor[i]  = o;
}

__global__ __launch_bounds__(256) void scatter_kernel(
    const int* __restrict__ row, const int* __restrict__ col,
    const float* __restrict__ val, int* __restrict__ cursor,
    uint2* __restrict__ edata, int E)
{
    int e = blockIdx.x * 256 + threadIdx.x;
    if (e >= E) return;
    int r = row[e];
    int pos = atomicAdd(&cursor[r], 1);
    uint2 d;
    d.x = (unsigned)col[e];
    d.y = __float_as_uint(val[e]);
    edata[pos] = d;
}

// ---------------------------------------------------------------------------
// pull SpMM: one wave per row, lane = emb dim, 8-deep ILP, bf16 emb table
// ---------------------------------------------------------------------------
__global__ __launch_bounds__(256) void pull_kernel(
    const int* __restrict__ offsets, const int* __restrict__ counts,
    const uint2* __restrict__ edata, const unsigned short* __restrict__ embb,
    unsigned short* __restrict__ xb, int Nn)
{
    int r    = blockIdx.x * 4 + (threadIdx.x >> 6);
    int lane = threadIdx.x & 63;
    if (r >= Nn) return;
    int beg = offsets[r];
    int cnt = counts[r];
    float acc = 0.f;
    for (int i = 0; i < cnt; i += 8) {
        uint2 ed[8];
#pragma unroll
        for (int j = 0; j < 8; ++j) {
            int idx = i + j;
            idx = (idx < cnt) ? idx : (cnt - 1);
            ed[j] = edata[beg + idx];
        }
        float g[8];
#pragma unroll
        for (int j = 0; j < 8; ++j)
            g[j] = bf2f(embb[(size_t)ed[j].x * EMB + lane]);
#pragma unroll
        for (int j = 0; j < 8; ++j) {
            float v = (i + j < cnt) ? __uint_as_float(ed[j].y) : 0.f;
            acc += v * g[j];
        }
    }
    xb[(size_t)r * EMB + lane] = f2bf(acc);
}

// ---------------------------------------------------------------------------
// fused 3-layer MLP: out = relu(relu(x@W0)@W1)@W2
// block = 256 thr (4 waves), 64 rows, full 256-col width.
// LDS: As (x K-chunk), Bs (streamed W0t/W1t/W2t chunks), H (h0 -> h1 in place).
// ---------------------------------------------------------------------------
__global__ __launch_bounds__(256) void mlp_fused(
    const unsigned short* __restrict__ xb,   // [M][64]  bf16
    const unsigned short* __restrict__ W0t,  // [256][64]
    const unsigned short* __restrict__ W1t,  // [256][256]
    const unsigned short* __restrict__ W2t,  // [256][256]
    float* __restrict__ out, int M)
{
    constexpr int LDK = 72;    // 64-wide K chunk, +8 pad
    constexpr int LDH = 264;   // 256-wide hidden row, +8 pad
    __shared__ unsigned short As[64 * LDK];   //  9.2 KB
    __shared__ unsigned short Bs[256 * LDK];  // 36.9 KB
    __shared__ unsigned short H [64 * LDH];   // 33.8 KB

    const int t    = threadIdx.x;
    const int lane = t & 63;
    const int w    = t >> 6;
    const int lr   = lane & 15;
    const int kg   = lane >> 4;
    const int row0 = blockIdx.x * 64;

    // ---------------- phase 1: h0 = relu(x @ W0), K = 64 ----------------
#pragma unroll
    for (int c = 0; c < 2; ++c) {             // stage x tile 64x64
        int chunk = t + c * 256;
        int r = chunk >> 3, ko = (chunk & 7) * 8;
        int gr = row0 + r;
        *(short8_t*)&As[r * LDK + ko] =
            *(const short8_t*)(xb + (size_t)(gr < M ? gr : 0) * EMB + ko);
    }
#pragma unroll
    for (int c = 0; c < 8; ++c) {             // stage W0t 256x64
        int chunk = t + c * 256;
        int n = chunk >> 3, ko = (chunk & 7) * 8;
        *(short8_t*)&Bs[n * LDK + ko] = *(const short8_t*)(W0t + n * EMB + ko);
    }
    __syncthreads();

    f32x4 acc[4][4] = {};
#pragma unroll
    for (int ks = 0; ks < 64; ks += 32) {
        short8_t a[4], b[4];
#pragma unroll
        for (int m = 0; m < 4; ++m)
            a[m] = *(const short8_t*)&As[(m * 16 + lr) * LDK + ks + kg * 8];
#pragma unroll
        for (int n = 0; n < 4; ++n)
            b[n] = *(const short8_t*)&Bs[(w * 64 + n * 16 + lr) * LDK + ks + kg * 8];
#pragma unroll
        for (int m = 0; m < 4; ++m)
#pragma unroll
            for (int n = 0; n < 4; ++n)
                acc[m][n] = __builtin_amdgcn_mfma_f32_16x16x32_bf16(
                    a[m], b[n], acc[m][n], 0, 0, 0);
    }
    // write h0 -> H (relu). D map: col=lane&15, row=(lane>>4)*4+reg
#pragma unroll
    for (int m = 0; m < 4; ++m)
#pragma unroll
        for (int r = 0; r < 4; ++r)
#pragma unroll
            for (int n = 0; n < 4; ++n)
                H[(m * 16 + kg * 4 + r) * LDH + w * 64 + n * 16 + lr] =
                    f2bf(fmaxf(acc[m][n][r], 0.f));
    __syncthreads();   // phase1 Bs reads done + H visible

    // ---------------- phase 2: h1 = relu(h0 @ W1), K = 256 ----------------
    f32x4 acc2[4][4] = {};
    for (int k0 = 0; k0 < HID; k0 += 64) {
#pragma unroll
        for (int c = 0; c < 8; ++c) {         // stage W1t chunk [256][64]
            int chunk = t + c * 256;
            int n = chunk >> 3, ko = (chunk & 7) * 8;
            *(short8_t*)&Bs[n * LDK + ko] =
                *(const short8_t*)(W1t + (size_t)n * HID + k0 + ko);
        }
        __syncthreads();
#pragma unroll
        for (int ks = 0; ks < 64; ks += 32) {
            short8_t a[4], b[4];
#pragma unroll
            for (int m = 0; m < 4; ++m)
                a[m] = *(const short8_t*)&H[(m * 16 + lr) * LDH + k0 + ks + kg * 8];
#pragma unroll
            for (int n = 0; n < 4; ++n)
                b[n] = *(const short8_t*)&Bs[(w * 64 + n * 16 + lr) * LDK + ks + kg * 8];
#pragma unroll
            for (int m = 0; m < 4; ++m)
#pragma unroll
                for (int n = 0; n < 4; ++n)
                    acc2[m][n] = __builtin_amdgcn_mfma_f32_16x16x32_bf16(
                        a[m], b[n], acc2[m][n], 0, 0, 0);
        }
        __syncthreads();                      // H/Bs reads done before next stage
    }
    // write h1 -> H in place (all h0 reads completed at the barrier above)
#pragma unroll
    for (int m = 0; m < 4; ++m)
#pragma unroll
        for (int r = 0; r < 4; ++r)
#pragma unroll
            for (int n = 0; n < 4; ++n)
                H[(m * 16 + kg * 4 + r) * LDH + w * 64 + n * 16 + lr] =
                    f2bf(fmaxf(acc2[m][n][r], 0.f));

    // ---------------- phase 3: out = h1 @ W2, K = 256 ----------------
    f32x4 acc3[4][4] = {};
    for (int k0 = 0; k0 < HID; k0 += 64) {
#pragma unroll
        for (int c = 0; c < 8; ++c) {         // stage W2t chunk
            int chunk = t + c * 256;
            int n = chunk >> 3, ko = (chunk & 7) * 8;
            *(short8_t*)&Bs[n * LDK + ko] =
                *(const short8_t*)(W2t + (size_t)n * HID + k0 + ko);
        }
        __syncthreads();                      // also makes h1 writes visible (k0==0)
#pragma unroll
        for (int ks = 0; ks < 64; ks += 32) {
            short8_t a[4], b[4];
#pragma unroll
            for (int m = 0; m < 4; ++m)
                a[m] = *(const short8_t*)&H[(m * 16 + lr) * LDH + k0 + ks + kg * 8];
#pragma unroll
            for (int n = 0; n < 4; ++n)
                b[n] = *(const short8_t*)&Bs[(w * 64 + n * 16 + lr) * LDK + ks + kg * 8];
#pragma unroll
            for (int m = 0; m < 4; ++m)
#pragma unroll
                for (int n = 0; n < 4; ++n)
                    acc3[m][n] = __builtin_amdgcn_mfma_f32_16x16x32_bf16(
                        a[m], b[n], acc3[m][n], 0, 0, 0);
        }
        __syncthreads();
    }
    // epilogue: fp32 out
#pragma unroll
    for (int m = 0; m < 4; ++m)
#pragma unroll
        for (int r = 0; r < 4; ++r) {
            int gr = row0 + m * 16 + kg * 4 + r;
            if (gr < M)
#pragma unroll
                for (int n = 0; n < 4; ++n)
                    out[(size_t)gr * HID + w * 64 + n * 16 + lr] = acc3[m][n][r];
        }
}

// ---------------------------------------------------------------------------
// fallback path kernels (ws too small): atomic scatter SpMM + fp32 GEMM
// ---------------------------------------------------------------------------
__global__ __launch_bounds__(256) void spmm_kernel(
    const int* __restrict__ row, const int* __restrict__ col,
    const float* __restrict__ val, const float* __restrict__ emb,
    float* __restrict__ x, int E)
{
    int gid  = blockIdx.x * blockDim.x + threadIdx.x;
    int e    = gid >> 6;
    int lane = gid & 63;
    if (e >= E) return;
    unsafeAtomicAdd(&x[(size_t)row[e] * EMB + lane],
                    val[e] * emb[(size_t)col[e] * EMB + lane]);
}

template<int K, bool RELU>
__global__ __launch_bounds__(256) void gemm_f32(
    const float* A, const float* __restrict__ B, float* C, int M)
{
    __shared__ float As[64][17];
    __shared__ float Bs[16][256];

    const int t    = threadIdx.x;
    const int tn   = t & 15;
    const int row0 = blockIdx.x * 64;
    const int sk = t & 15;
    const int sm = (t >> 4) * 4;

    float acc[4][16];
#pragma unroll
    for (int i = 0; i < 4; ++i)
#pragma unroll
        for (int j = 0; j < 16; ++j) acc[i][j] = 0.f;

    const int mB = ((t & 63) >> 4) * 4;
    const int wq = t >> 6;
    const int myM = (wq * 16) + mB;

    for (int k0 = 0; k0 < K; k0 += 16) {
        __syncthreads();
#pragma unroll
        for (int i = 0; i < 4; ++i) {
            int m  = sm + i;
            int gr = row0 + m;
            As[m][sk] = (gr < M) ? A[(size_t)gr * K + k0 + sk] : 0.f;
        }
#pragma unroll
        for (int r = 0; r < 16; ++r)
            Bs[r][t] = B[(size_t)(k0 + r) * 256 + t];
        __syncthreads();

#pragma unroll
        for (int kk = 0; kk < 16; ++kk) {
            float a0 = As[myM + 0][kk];
            float a1 = As[myM + 1][kk];
            float a2 = As[myM + 2][kk];
            float a3 = As[myM + 3][kk];
            float4 b[4];
#pragma unroll
            for (int j = 0; j < 4; ++j)
                b[j] = *(const float4*)&Bs[kk][tn * 4 + j * 64];
#pragma unroll
            for (int j = 0; j < 4; ++j) {
                acc[0][j*4+0] += a0 * b[j].x;  acc[0][j*4+1] += a0 * b[j].y;
                acc[0][j*4+2] += a0 * b[j].z;  acc[0][j*4+3] += a0 * b[j].w;
                acc[1][j*4+0] += a1 * b[j].x;  acc[1][j*4+1] += a1 * b[j].y;
                acc[1][j*4+2] += a1 * b[j].z;  acc[1][j*4+3] += a1 * b[j].w;
                acc[2][j*4+0] += a2 * b[j].x;  acc[2][j*4+1] += a2 * b[j].y;
                acc[2][j*4+2] += a2 * b[j].z;  acc[2][j*4+3] += a2 * b[j].w;
                acc[3][j*4+0] += a3 * b[j].x;  acc[3][j*4+1] += a3 * b[j].y;
                acc[3][j*4+2] += a3 * b[j].z;  acc[3][j*4+3] += a3 * b[j].w;
            }
        }
    }

#pragma unroll
    for (int i = 0; i < 4; ++i) {
        int gr = row0 + myM + i;
        if (gr < M) {
#pragma unroll
            for (int j = 0; j < 4; ++j) {
                float4 o;
                o.x = acc[i][j*4+0]; o.y = acc[i][j*4+1];
                o.z = acc[i][j*4+2]; o.w = acc[i][j*4+3];
                if (RELU) {
                    o.x = fmaxf(o.x, 0.f); o.y = fmaxf(o.y, 0.f);
                    o.z = fmaxf(o.z, 0.f); o.w = fmaxf(o.w, 0.f);
                }
                *(float4*)&C[(size_t)gr * 256 + tn * 4 + j * 64] = o;
            }
        }
    }
}

extern "C" void kernel_launch(void* const* d_in, const int* in_sizes, int n_in,
                              void* d_out, int out_size, void* d_ws, size_t ws_size,
                              hipStream_t stream)
{
    const int*   row = (const int*)d_in[0];
    const int*   col = (const int*)d_in[1];
    const float* val = (const float*)d_in[2];
    const float* emb = (const float*)d_in[3];
    const float* W0  = (const float*)d_in[4];
    const float* W1  = (const float*)d_in[5];
    const float* W2  = (const float*)d_in[6];
    float* out = (float*)d_out;

    const int E = in_sizes[0];
    const int M = in_sizes[3] / EMB;   // num nodes

    char* ws = (char*)d_ws;

    // ---- ws layout (256B-aligned regions) ----
    size_t off = 0;
    auto alloc = [&](size_t bytes) { size_t o = off; off = (off + bytes + 255) & ~(size_t)255; return o; };
    const size_t off_counts = alloc((size_t)M * 4);
    const size_t off_offs   = alloc((size_t)M * 4);
    const size_t off_cursor = alloc((size_t)M * 4);
    const size_t off_bsums  = alloc(1024);
    const size_t off_edata  = alloc((size_t)E * 8);
    const size_t off_embb   = alloc((size_t)M * EMB * 2);
    const size_t off_xb     = alloc((size_t)M * EMB * 2);
    const size_t off_w0     = alloc((size_t)EMB * HID * 2);
    const size_t off_w1     = alloc((size_t)HID * HID * 2);
    const size_t off_w2     = alloc((size_t)HID * HID * 2);
    const size_t need       = off;

    int gblocks = (M + 63) / 64;

    if (ws_size >= need) {
        int*   counts = (int*)(ws + off_counts);
        int*   offs   = (int*)(ws + off_offs);
        int*   cursor = (int*)(ws + off_cursor);
        int*   bsums  = (int*)(ws + off_bsums);
        uint2* edata  = (uint2*)(ws + off_edata);
        unsigned short* embb = (unsigned short*)(ws + off_embb);
        unsigned short* xb  = (unsigned short*)(ws + off_xb);
        unsigned short* W0t = (unsigned short*)(ws + off_w0);
        unsigned short* W1t = (unsigned short*)(ws + off_w1);
        unsigned short* W2t = (unsigned short*)(ws + off_w2);

        // fused prep: zero counts + emb->bf16 + weight transpose/cvt
        int zb = (M / 4 + 255) / 256;
        int cb = ((M * EMB) / 4 + 255) / 256;
        int prep_blocks = zb + cb + EMB + HID + HID;
        prep_kernel<<<prep_blocks, 256, 0, stream>>>(
            emb, W0, W1, W2, counts, embb, W0t, W1t, W2t, M, zb, cb);

        // CSR build
        hist_kernel<<<(E / 4 + 255) / 256, 256, 0, stream>>>(row, counts, E);
        int nb = (M + 1023) / 1024;
        scan_phase1<<<nb, 256, 0, stream>>>(counts, offs, bsums, M);
        scan_phase2<<<1, 256, 0, stream>>>(bsums, nb);
        scan_phase3<<<(M + 255) / 256, 256, 0, stream>>>(offs, bsums, cursor, M);
        scatter_kernel<<<(E + 255) / 256, 256, 0, stream>>>(row, col, val, cursor, edata, E);

        // pull SpMM -> xb (bf16)
        pull_kernel<<<(M + 3) / 4, 256, 0, stream>>>(offs, counts, edata, embb, xb, M);

        // fused 3-layer MLP -> out
        mlp_fused<<<gblocks, 256, 0, stream>>>(xb, W0t, W1t, W2t, out, M);
    } else {
        // fp32 fallback (ws too small): atomic scatter SpMM + fp32 GEMMs
        float* x = (float*)ws;
        (void)hipMemsetAsync(x, 0, (size_t)M * EMB * sizeof(float), stream);
        spmm_kernel<<<(E + 3) / 4, 256, 0, stream>>>(row, col, val, emb, x, E);
        gemm_f32<EMB, true ><<<gblocks, 256, 0, stream>>>(x,   W0, out, M);
        gemm_f32<HID, true ><<<gblocks, 256, 0, stream>>>(out, W1, out, M);
        gemm_f32<HID, false><<<gblocks, 256, 0, stream>>>(out, W2, out, M);
    }
}

// Round 9
// 201.320 us; speedup vs baseline: 3.0691x; 1.0112x over previous
//
#include <hip/hip_runtime.h>
#include <hip/hip_bf16.h>

#define EMB 64
#define HID 256

typedef __attribute__((ext_vector_type(8))) short short8_t;   // 8 bf16 = 4 VGPRs
typedef __attribute__((ext_vector_type(4))) float f32x4;

// fp32 -> bf16 bits, round-to-nearest-even (matches HW conversion)
__device__ __forceinline__ unsigned short f2bf(float f)
{
    union { float f; unsigned int u; } c; c.f = f;
    unsigned int u = c.u;
    u += 0x7fffu + ((u >> 16) & 1u);
    return (unsigned short)(u >> 16);
}
__device__ __forceinline__ float bf2f(unsigned short b)
{
    union { unsigned int u; float f; } c; c.u = ((unsigned int)b) << 16;
    return c.f;
}

// ---------------------------------------------------------------------------
// prep: block-range fused {zero counts | emb->bf16 | W0/W1/W2 transpose+cvt}
// ---------------------------------------------------------------------------
__global__ __launch_bounds__(256) void prep_kernel(
    const float* __restrict__ emb, const float* __restrict__ W0,
    const float* __restrict__ W1, const float* __restrict__ W2,
    int* __restrict__ counts, unsigned short* __restrict__ embb,
    unsigned short* __restrict__ W0t, unsigned short* __restrict__ W1t,
    unsigned short* __restrict__ W2t, int M, int zb, int cb)
{
    int b = blockIdx.x;
    if (b < zb) {                              // zero counts[M]
        int idx = (b * 256 + threadIdx.x) * 4;
        if (idx + 3 < M) {
            int4 z; z.x = 0; z.y = 0; z.z = 0; z.w = 0;
            *(int4*)&counts[idx] = z;
        } else {
            for (int i = idx; i < M; ++i) counts[i] = 0;
        }
        return;
    }
    b -= zb;
    if (b < cb) {                              // emb fp32 -> bf16
        int idx = (b * 256 + threadIdx.x) * 4;
        if (idx + 3 < M * EMB) {
            float4 v = *(const float4*)&emb[idx];
            ushort4 o;
            o.x = f2bf(v.x); o.y = f2bf(v.y); o.z = f2bf(v.z); o.w = f2bf(v.w);
            *(ushort4*)&embb[idx] = o;
        }
        return;
    }
    b -= cb;
    if (b < EMB) {                             // W0 [64][256] -> W0t [256][64]
        int i = b * 256 + threadIdx.x;
        int k = i >> 8, n = i & 255;
        W0t[n * EMB + k] = f2bf(W0[i]);
        return;
    }
    b -= EMB;
    if (b < HID) {                             // W1 [256][256] -> W1t
        int i = b * 256 + threadIdx.x;
        int k = i >> 8, n = i & 255;
        W1t[n * HID + k] = f2bf(W1[i]);
        return;
    }
    b -= HID;
    {                                          // W2 [256][256] -> W2t
        int i = b * 256 + threadIdx.x;
        int k = i >> 8, n = i & 255;
        W2t[n * HID + k] = f2bf(W2[i]);
    }
}

// ---------------------------------------------------------------------------
// CSR build: histogram -> exclusive scan -> bucket scatter
// ---------------------------------------------------------------------------
__global__ __launch_bounds__(256) void hist_kernel(
    const int* __restrict__ row, int* __restrict__ counts, int E)
{
    int base = (blockIdx.x * 256 + threadIdx.x) * 4;
    if (base + 3 < E) {
        int4 r4 = *(const int4*)&row[base];
        atomicAdd(&counts[r4.x], 1);
        atomicAdd(&counts[r4.y], 1);
        atomicAdd(&counts[r4.z], 1);
        atomicAdd(&counts[r4.w], 1);
    } else {
        for (int i = base; i < E; ++i) atomicAdd(&counts[row[i]], 1);
    }
}

__global__ __launch_bounds__(256) void scan_phase1(
    const int* __restrict__ counts, int* __restrict__ excl,
    int* __restrict__ blockSums, int n)
{
    __shared__ int s[256];
    int t = threadIdx.x;
    int base = blockIdx.x * 1024 + t * 4;
    int4 v = {0, 0, 0, 0};
    if (base + 3 < n) {
        v = *(const int4*)&counts[base];
    } else {
        if (base + 0 < n) v.x = counts[base + 0];
        if (base + 1 < n) v.y = counts[base + 1];
        if (base + 2 < n) v.z = counts[base + 2];
        if (base + 3 < n) v.w = counts[base + 3];
    }
    int tsum = v.x + v.y + v.z + v.w;
    s[t] = tsum;
    __syncthreads();
#pragma unroll
    for (int off = 1; off < 256; off <<= 1) {
        int val = (t >= off) ? s[t - off] : 0;
        __syncthreads();
        s[t] += val;
        __syncthreads();
    }
    if (t == 255) blockSums[blockIdx.x] = s[255];
    int e0 = s[t] - tsum;
    int e1 = e0 + v.x;
    int e2 = e1 + v.y;
    int e3 = e2 + v.z;
    if (base + 0 < n) excl[base + 0] = e0;
    if (base + 1 < n) excl[base + 1] = e1;
    if (base + 2 < n) excl[base + 2] = e2;
    if (base + 3 < n) excl[base + 3] = e3;
}

__global__ __launch_bounds__(256) void scan_phase2(int* blockSums, int nb)
{
    __shared__ int s[256];
    int t = threadIdx.x;
    int v = (t < nb) ? blockSums[t] : 0;
    s[t] = v;
    __syncthreads();
#pragma unroll
    for (int off = 1; off < 256; off <<= 1) {
        int val = (t >= off) ? s[t - off] : 0;
        __syncthreads();
        s[t] += val;
        __syncthreads();
    }
    if (t < nb) blockSums[t] = s[t] - v;
}

__global__ __launch_bounds__(256) void scan_phase3(
    int* __restrict__ offsets, const int* __restrict__ blockSums,
    int* __restrict__ cursor, int n)
{
    int i = blockIdx.x * 256 + threadIdx.x;
    if (i >= n) return;
    int o = offsets[i] + blockSums[i >> 10];
    offsets[i] = o;
    cursor[i]  = o;
}

__global__ __launch_bounds__(256) void scatter_kernel(
    const int* __restrict__ row, const int* __restrict__ col,
    const float* __restrict__ val, int* __restrict__ cursor,
    uint2* __restrict__ edata, int E)
{
    int e = blockIdx.x * 256 + threadIdx.x;
    if (e >= E) return;
    int r = row[e];
    int pos = atomicAdd(&cursor[r], 1);
    uint2 d;
    d.x = (unsigned)col[e];
    d.y = __float_as_uint(val[e]);
    edata[pos] = d;
}

// ---------------------------------------------------------------------------
// pull SpMM: one wave per row, lane = emb dim, 8-deep ILP, bf16 emb table
// ---------------------------------------------------------------------------
__global__ __launch_bounds__(256) void pull_kernel(
    const int* __restrict__ offsets, const int* __restrict__ counts,
    const uint2* __restrict__ edata, const unsigned short* __restrict__ embb,
    unsigned short* __restrict__ xb, int Nn)
{
    int r    = blockIdx.x * 4 + (threadIdx.x >> 6);
    int lane = threadIdx.x & 63;
    if (r >= Nn) return;
    int beg = offsets[r];
    int cnt = counts[r];
    float acc = 0.f;
    for (int i = 0; i < cnt; i += 8) {
        uint2 ed[8];
#pragma unroll
        for (int j = 0; j < 8; ++j) {
            int idx = i + j;
            idx = (idx < cnt) ? idx : (cnt - 1);
            ed[j] = edata[beg + idx];
        }
        float g[8];
#pragma unroll
        for (int j = 0; j < 8; ++j)
            g[j] = bf2f(embb[(size_t)ed[j].x * EMB + lane]);
#pragma unroll
        for (int j = 0; j < 8; ++j) {
            float v = (i + j < cnt) ? __uint_as_float(ed[j].y) : 0.f;
            acc += v * g[j];
        }
    }
    xb[(size_t)r * EMB + lane] = f2bf(acc);
}

// ---------------------------------------------------------------------------
// fused 3-layer MLP, software-pipelined:
// out = relu(relu(x@W0)@W1)@W2
// block = 256 thr (4 waves), 64 rows, full 256-col width.
// K-chunk = 32, double-buffered W staging Bs[2]; x-tile in registers;
// H (h0 -> h1 in place) in LDS. One barrier per chunk; the global->reg load
// for chunk i+2 is issued in chunk i and ds_written in chunk i+1, so L2
// latency hides under compute.
// ---------------------------------------------------------------------------
__global__ __launch_bounds__(256) void mlp_fused(
    const unsigned short* __restrict__ xb,   // [M][64]  bf16
    const unsigned short* __restrict__ W0t,  // [256][64]
    const unsigned short* __restrict__ W1t,  // [256][256]
    const unsigned short* __restrict__ W2t,  // [256][256]
    float* __restrict__ out, int M)
{
    constexpr int LDK = 40;    // 32 k + 8 pad  (80B stride -> 2-way = free)
    constexpr int LDH = 264;   // 256 + 8 pad   (528B stride -> 2-way reads)
    __shared__ unsigned short Bs[2][256 * LDK];  // 2 x 20.0 KB
    __shared__ unsigned short H [64 * LDH];      // 33.8 KB  (total 74.8 KB)

    const int t    = threadIdx.x;
    const int lane = t & 63;
    const int w    = t >> 6;
    const int lr   = lane & 15;
    const int kg   = lane >> 4;
    const int row0 = blockIdx.x * 64;

    // staging decomposition: one chunk = 256 rows x 32 cols; 1024 granules of
    // 8 ushorts. instr c: thread t handles row 64c + (t>>2), granule t&3.
    const int srow = t >> 2;
    const int sq   = (t & 3) * 8;

    short8_t st[4];   // staged chunk in regs
#define LOADC(src, ldk, k0)                                                    \
    do {                                                                       \
        _Pragma("unroll")                                                      \
        for (int c = 0; c < 4; ++c)                                            \
            st[c] = *(const short8_t*)((src) + (size_t)(64 * c + srow) * (ldk) \
                                       + (k0) + sq);                           \
    } while (0)
#define WRITEC(buf)                                                            \
    do {                                                                       \
        _Pragma("unroll")                                                      \
        for (int c = 0; c < 4; ++c)                                            \
            *(short8_t*)&Bs[buf][(64 * c + srow) * LDK + sq] = st[c];          \
    } while (0)

    // x-tile A-fragments -> registers (rows m*16+lr, cols h*32 + kg*8)
    short8_t ax[2][4];
#pragma unroll
    for (int h = 0; h < 2; ++h)
#pragma unroll
        for (int m = 0; m < 4; ++m) {
            int gr = row0 + m * 16 + lr;
            ax[h][m] = *(const short8_t*)(xb + (size_t)(gr < M ? gr : 0) * EMB
                                          + h * 32 + kg * 8);
        }

    // prologue: stage W0 (2 chunks) into both buffers; preload W1c0 to regs
    LOADC(W0t, EMB, 0);  WRITEC(0);
    LOADC(W0t, EMB, 32); WRITEC(1);
    __syncthreads();
    LOADC(W1t, HID, 0);            // st regs free; W1c0 load in flight

    // ---------------- phase 1: h0 = relu(x @ W0) ----------------
    f32x4 acc[4][4] = {};
#pragma unroll
    for (int h = 0; h < 2; ++h) {
        short8_t b[4];
#pragma unroll
        for (int n = 0; n < 4; ++n)
            b[n] = *(const short8_t*)&Bs[h][(w * 64 + n * 16 + lr) * LDK + kg * 8];
#pragma unroll
        for (int m = 0; m < 4; ++m)
#pragma unroll
            for (int n = 0; n < 4; ++n)
                acc[m][n] = __builtin_amdgcn_mfma_f32_16x16x32_bf16(
                    ax[h][m], b[n], acc[m][n], 0, 0, 0);
    }
#pragma unroll
    for (int m = 0; m < 4; ++m)
#pragma unroll
        for (int r = 0; r < 4; ++r)
#pragma unroll
            for (int n = 0; n < 4; ++n)
                H[(m * 16 + kg * 4 + r) * LDH + w * 64 + n * 16 + lr] =
                    f2bf(fmaxf(acc[m][n][r], 0.f));
    __syncthreads();               // phase-1 Bs reads done; H(h0) visible

    WRITEC(0);                     // Bs[0] = W1c0
    LOADC(W1t, HID, 32);           // regs  = W1c1
    __syncthreads();               // Bs[0] ready

    // ---------------- phase 2: h1 = relu(h0 @ W1), 8 chunks ----------------
    f32x4 acc2[4][4] = {};
    for (int i = 0; i < 8; ++i) {
        int cur = i & 1;
        short8_t a[4], b[4];
#pragma unroll
        for (int m = 0; m < 4; ++m)
            a[m] = *(const short8_t*)&H[(m * 16 + lr) * LDH + i * 32 + kg * 8];
#pragma unroll
        for (int n = 0; n < 4; ++n)
            b[n] = *(const short8_t*)&Bs[cur][(w * 64 + n * 16 + lr) * LDK + kg * 8];
#pragma unroll
        for (int m = 0; m < 4; ++m)
#pragma unroll
            for (int n = 0; n < 4; ++n)
                acc2[m][n] = __builtin_amdgcn_mfma_f32_16x16x32_bf16(
                    a[m], b[n], acc2[m][n], 0, 0, 0);
        WRITEC(cur ^ 1);                       // stage chunk i+1
        if (i < 6) {
            LOADC(W1t, HID, (i + 2) * 32);
        } else if (i == 6) {
            LOADC(W2t, HID, 0);                // chunk 8 = W2c0
        } else {
            LOADC(W2t, HID, 32);               // chunk 9 = W2c1
        }
        __syncthreads();
    }
    // write h1 -> H in place (all H reads finished at the last barrier)
#pragma unroll
    for (int m = 0; m < 4; ++m)
#pragma unroll
        for (int r = 0; r < 4; ++r)
#pragma unroll
            for (int n = 0; n < 4; ++n)
                H[(m * 16 + kg * 4 + r) * LDH + w * 64 + n * 16 + lr] =
                    f2bf(fmaxf(acc2[m][n][r], 0.f));
    __syncthreads();               // h1 visible; Bs[0]=W2c0 staged, regs=W2c1

    // ---------------- phase 3: out = h1 @ W2, 8 chunks ----------------
    f32x4 acc3[4][4] = {};
    for (int i = 0; i < 8; ++i) {
        int cur = i & 1;
        short8_t a[4], b[4];
#pragma unroll
        for (int m = 0; m < 4; ++m)
            a[m] = *(const short8_t*)&H[(m * 16 + lr) * LDH + i * 32 + kg * 8];
#pragma unroll
        for (int n = 0; n < 4; ++n)
            b[n] = *(const short8_t*)&Bs[cur][(w * 64 + n * 16 + lr) * LDK + kg * 8];
#pragma unroll
        for (int m = 0; m < 4; ++m)
#pragma unroll
            for (int n = 0; n < 4; ++n)
                acc3[m][n] = __builtin_amdgcn_mfma_f32_16x16x32_bf16(
                    a[m], b[n], acc3[m][n], 0, 0, 0);
        if (i < 7) {
            WRITEC(cur ^ 1);
            if (i < 6) {
                LOADC(W2t, HID, (i + 2) * 32);
            }
            __syncthreads();
        }
    }
    // epilogue: fp32 out
#pragma unroll
    for (int m = 0; m < 4; ++m)
#pragma unroll
        for (int r = 0; r < 4; ++r) {
            int gr = row0 + m * 16 + kg * 4 + r;
            if (gr < M)
#pragma unroll
                for (int n = 0; n < 4; ++n)
                    out[(size_t)gr * HID + w * 64 + n * 16 + lr] = acc3[m][n][r];
        }
#undef LOADC
#undef WRITEC
}

// ---------------------------------------------------------------------------
// fallback path kernels (ws too small): atomic scatter SpMM + fp32 GEMM
// ---------------------------------------------------------------------------
__global__ __launch_bounds__(256) void spmm_kernel(
    const int* __restrict__ row, const int* __restrict__ col,
    const float* __restrict__ val, const float* __restrict__ emb,
    float* __restrict__ x, int E)
{
    int gid  = blockIdx.x * blockDim.x + threadIdx.x;
    int e    = gid >> 6;
    int lane = gid & 63;
    if (e >= E) return;
    unsafeAtomicAdd(&x[(size_t)row[e] * EMB + lane],
                    val[e] * emb[(size_t)col[e] * EMB + lane]);
}

template<int K, bool RELU>
__global__ __launch_bounds__(256) void gemm_f32(
    const float* A, const float* __restrict__ B, float* C, int M)
{
    __shared__ float As[64][17];
    __shared__ float Bs[16][256];

    const int t    = threadIdx.x;
    const int tn   = t & 15;
    const int row0 = blockIdx.x * 64;
    const int sk = t & 15;
    const int sm = (t >> 4) * 4;

    float acc[4][16];
#pragma unroll
    for (int i = 0; i < 4; ++i)
#pragma unroll
        for (int j = 0; j < 16; ++j) acc[i][j] = 0.f;

    const int mB = ((t & 63) >> 4) * 4;
    const int wq = t >> 6;
    const int myM = (wq * 16) + mB;

    for (int k0 = 0; k0 < K; k0 += 16) {
        __syncthreads();
#pragma unroll
        for (int i = 0; i < 4; ++i) {
            int m  = sm + i;
            int gr = row0 + m;
            As[m][sk] = (gr < M) ? A[(size_t)gr * K + k0 + sk] : 0.f;
        }
#pragma unroll
        for (int r = 0; r < 16; ++r)
            Bs[r][t] = B[(size_t)(k0 + r) * 256 + t];
        __syncthreads();

#pragma unroll
        for (int kk = 0; kk < 16; ++kk) {
            float a0 = As[myM + 0][kk];
            float a1 = As[myM + 1][kk];
            float a2 = As[myM + 2][kk];
            float a3 = As[myM + 3][kk];
            float4 b[4];
#pragma unroll
            for (int j = 0; j < 4; ++j)
                b[j] = *(const float4*)&Bs[kk][tn * 4 + j * 64];
#pragma unroll
            for (int j = 0; j < 4; ++j) {
                acc[0][j*4+0] += a0 * b[j].x;  acc[0][j*4+1] += a0 * b[j].y;
                acc[0][j*4+2] += a0 * b[j].z;  acc[0][j*4+3] += a0 * b[j].w;
                acc[1][j*4+0] += a1 * b[j].x;  acc[1][j*4+1] += a1 * b[j].y;
                acc[1][j*4+2] += a1 * b[j].z;  acc[1][j*4+3] += a1 * b[j].w;
                acc[2][j*4+0] += a2 * b[j].x;  acc[2][j*4+1] += a2 * b[j].y;
                acc[2][j*4+2] += a2 * b[j].z;  acc[2][j*4+3] += a2 * b[j].w;
                acc[3][j*4+0] += a3 * b[j].x;  acc[3][j*4+1] += a3 * b[j].y;
                acc[3][j*4+2] += a3 * b[j].z;  acc[3][j*4+3] += a3 * b[j].w;
            }
        }
    }

#pragma unroll
    for (int i = 0; i < 4; ++i) {
        int gr = row0 + myM + i;
        if (gr < M) {
#pragma unroll
            for (int j = 0; j < 4; ++j) {
                float4 o;
                o.x = acc[i][j*4+0]; o.y = acc[i][j*4+1];
                o.z = acc[i][j*4+2]; o.w = acc[i][j*4+3];
                if (RELU) {
                    o.x = fmaxf(o.x, 0.f); o.y = fmaxf(o.y, 0.f);
                    o.z = fmaxf(o.z, 0.f); o.w = fmaxf(o.w, 0.f);
                }
                *(float4*)&C[(size_t)gr * 256 + tn * 4 + j * 64] = o;
            }
        }
    }
}

extern "C" void kernel_launch(void* const* d_in, const int* in_sizes, int n_in,
                              void* d_out, int out_size, void* d_ws, size_t ws_size,
                              hipStream_t stream)
{
    const int*   row = (const int*)d_in[0];
    const int*   col = (const int*)d_in[1];
    const float* val = (const float*)d_in[2];
    const float* emb = (const float*)d_in[3];
    const float* W0  = (const float*)d_in[4];
    const float* W1  = (const float*)d_in[5];
    const float* W2  = (const float*)d_in[6];
    float* out = (float*)d_out;

    const int E = in_sizes[0];
    const int M = in_sizes[3] / EMB;   // num nodes

    char* ws = (char*)d_ws;

    // ---- ws layout (256B-aligned regions) ----
    size_t off = 0;
    auto alloc = [&](size_t bytes) { size_t o = off; off = (off + bytes + 255) & ~(size_t)255; return o; };
    const size_t off_counts = alloc((size_t)M * 4);
    const size_t off_offs   = alloc((size_t)M * 4);
    const size_t off_cursor = alloc((size_t)M * 4);
    const size_t off_bsums  = alloc(1024);
    const size_t off_edata  = alloc((size_t)E * 8);
    const size_t off_embb   = alloc((size_t)M * EMB * 2);
    const size_t off_xb     = alloc((size_t)M * EMB * 2);
    const size_t off_w0     = alloc((size_t)EMB * HID * 2);
    const size_t off_w1     = alloc((size_t)HID * HID * 2);
    const size_t off_w2     = alloc((size_t)HID * HID * 2);
    const size_t need       = off;

    int gblocks = (M + 63) / 64;

    if (ws_size >= need) {
        int*   counts = (int*)(ws + off_counts);
        int*   offs   = (int*)(ws + off_offs);
        int*   cursor = (int*)(ws + off_cursor);
        int*   bsums  = (int*)(ws + off_bsums);
        uint2* edata  = (uint2*)(ws + off_edata);
        unsigned short* embb = (unsigned short*)(ws + off_embb);
        unsigned short* xb  = (unsigned short*)(ws + off_xb);
        unsigned short* W0t = (unsigned short*)(ws + off_w0);
        unsigned short* W1t = (unsigned short*)(ws + off_w1);
        unsigned short* W2t = (unsigned short*)(ws + off_w2);

        // fused prep: zero counts + emb->bf16 + weight transpose/cvt
        int zb = (M / 4 + 255) / 256;
        int cb = ((M * EMB) / 4 + 255) / 256;
        int prep_blocks = zb + cb + EMB + HID + HID;
        prep_kernel<<<prep_blocks, 256, 0, stream>>>(
            emb, W0, W1, W2, counts, embb, W0t, W1t, W2t, M, zb, cb);

        // CSR build
        hist_kernel<<<(E / 4 + 255) / 256, 256, 0, stream>>>(row, counts, E);
        int nb = (M + 1023) / 1024;
        scan_phase1<<<nb, 256, 0, stream>>>(counts, offs, bsums, M);
        scan_phase2<<<1, 256, 0, stream>>>(bsums, nb);
        scan_phase3<<<(M + 255) / 256, 256, 0, stream>>>(offs, bsums, cursor, M);
        scatter_kernel<<<(E + 255) / 256, 256, 0, stream>>>(row, col, val, cursor, edata, E);

        // pull SpMM -> xb (bf16)
        pull_kernel<<<(M + 3) / 4, 256, 0, stream>>>(offs, counts, edata, embb, xb, M);

        // fused 3-layer MLP -> out
        mlp_fused<<<gblocks, 256, 0, stream>>>(xb, W0t, W1t, W2t, out, M);
    } else {
        // fp32 fallback (ws too small): atomic scatter SpMM + fp32 GEMMs
        float* x = (float*)ws;
        (void)hipMemsetAsync(x, 0, (size_t)M * EMB * sizeof(float), stream);
        spmm_kernel<<<(E + 3) / 4, 256, 0, stream>>>(row, col, val, emb, x, E);
        gemm_f32<EMB, true ><<<gblocks, 256, 0, stream>>>(x,   W0, out, M);
        gemm_f32<HID, true ><<<gblocks, 256, 0, stream>>>(out, W1, out, M);
        gemm_f32<HID, false><<<gblocks, 256, 0, stream>>>(out, W2, out, M);
    }
}

// Round 10
// 200.963 us; speedup vs baseline: 3.0746x; 1.0018x over previous
//
#include <hip/hip_runtime.h>
#include <hip/hip_bf16.h>

#define EMB 64
#define HID 256

typedef __attribute__((ext_vector_type(8))) short short8_t;   // 8 bf16 = 4 VGPRs
typedef __attribute__((ext_vector_type(4))) float f32x4;

// fp32 -> bf16 bits, round-to-nearest-even (matches HW conversion)
__device__ __forceinline__ unsigned short f2bf(float f)
{
    union { float f; unsigned int u; } c; c.f = f;
    unsigned int u = c.u;
    u += 0x7fffu + ((u >> 16) & 1u);
    return (unsigned short)(u >> 16);
}
__device__ __forceinline__ float bf2f(unsigned short b)
{
    union { unsigned int u; float f; } c; c.u = ((unsigned int)b) << 16;
    return c.f;
}

// ---------------------------------------------------------------------------
// prep: fused {zero counts | emb->bf16 | W0/W1/W2 -> MFMA fragment-major bf16}
// Fragment-major: Wf[((nt*KC + kc)*64 + lane)*8 + j] = W[kc*32 + kg*8 + j][nt*16 + lr]
// where lane = kg*16 + lr.  A wave's B-fragment load for (n-tile nt, chunk kc)
// is then one coalesced 1KB read: &Wf[((nt*KC+kc)*64 + lane)*8].
// ---------------------------------------------------------------------------
__global__ __launch_bounds__(256) void prep_kernel(
    const float* __restrict__ emb, const float* __restrict__ W0,
    const float* __restrict__ W1, const float* __restrict__ W2,
    int* __restrict__ counts, unsigned short* __restrict__ embb,
    unsigned short* __restrict__ W0f, unsigned short* __restrict__ W1f,
    unsigned short* __restrict__ W2f, int M, int zb, int cb)
{
    int b = blockIdx.x;
    if (b < zb) {                              // zero counts[M]
        int idx = (b * 256 + threadIdx.x) * 4;
        if (idx + 3 < M) {
            int4 z; z.x = 0; z.y = 0; z.z = 0; z.w = 0;
            *(int4*)&counts[idx] = z;
        } else {
            for (int i = idx; i < M; ++i) counts[i] = 0;
        }
        return;
    }
    b -= zb;
    if (b < cb) {                              // emb fp32 -> bf16
        int idx = (b * 256 + threadIdx.x) * 4;
        if (idx + 3 < M * EMB) {
            float4 v = *(const float4*)&emb[idx];
            ushort4 o;
            o.x = f2bf(v.x); o.y = f2bf(v.y); o.z = f2bf(v.z); o.w = f2bf(v.w);
            *(ushort4*)&embb[idx] = o;
        }
        return;
    }
    b -= cb;
    if (b < 8) {                               // W0f: 16 nt x 2 kc x 64 lanes
        int i    = b * 256 + threadIdx.x;      // triple id
        int lane = i & 63;
        int kc   = (i >> 6) & 1;
        int nt   = i >> 7;
        int lr   = lane & 15, kg = lane >> 4;
        unsigned short tmp[8];
#pragma unroll
        for (int j = 0; j < 8; ++j)
            tmp[j] = f2bf(W0[(kc * 32 + kg * 8 + j) * HID + nt * 16 + lr]);
        *(short8_t*)&W0f[(size_t)i * 8] = *(short8_t*)tmp;
        return;
    }
    b -= 8;
    if (b < 32) {                              // W1f: 16 nt x 8 kc x 64 lanes
        int i    = b * 256 + threadIdx.x;
        int lane = i & 63;
        int kc   = (i >> 6) & 7;
        int nt   = i >> 9;
        int lr   = lane & 15, kg = lane >> 4;
        unsigned short tmp[8];
#pragma unroll
        for (int j = 0; j < 8; ++j)
            tmp[j] = f2bf(W1[(kc * 32 + kg * 8 + j) * HID + nt * 16 + lr]);
        *(short8_t*)&W1f[(size_t)i * 8] = *(short8_t*)tmp;
        return;
    }
    b -= 32;
    {                                          // W2f
        int i    = b * 256 + threadIdx.x;
        int lane = i & 63;
        int kc   = (i >> 6) & 7;
        int nt   = i >> 9;
        int lr   = lane & 15, kg = lane >> 4;
        unsigned short tmp[8];
#pragma unroll
        for (int j = 0; j < 8; ++j)
            tmp[j] = f2bf(W2[(kc * 32 + kg * 8 + j) * HID + nt * 16 + lr]);
        *(short8_t*)&W2f[(size_t)i * 8] = *(short8_t*)tmp;
    }
}

// ---------------------------------------------------------------------------
// CSR build: histogram -> exclusive scan -> bucket scatter
// ---------------------------------------------------------------------------
__global__ __launch_bounds__(256) void hist_kernel(
    const int* __restrict__ row, int* __restrict__ counts, int E)
{
    int base = (blockIdx.x * 256 + threadIdx.x) * 4;
    if (base + 3 < E) {
        int4 r4 = *(const int4*)&row[base];
        atomicAdd(&counts[r4.x], 1);
        atomicAdd(&counts[r4.y], 1);
        atomicAdd(&counts[r4.z], 1);
        atomicAdd(&counts[r4.w], 1);
    } else {
        for (int i = base; i < E; ++i) atomicAdd(&counts[row[i]], 1);
    }
}

__global__ __launch_bounds__(256) void scan_phase1(
    const int* __restrict__ counts, int* __restrict__ excl,
    int* __restrict__ blockSums, int n)
{
    __shared__ int s[256];
    int t = threadIdx.x;
    int base = blockIdx.x * 1024 + t * 4;
    int4 v = {0, 0, 0, 0};
    if (base + 3 < n) {
        v = *(const int4*)&counts[base];
    } else {
        if (base + 0 < n) v.x = counts[base + 0];
        if (base + 1 < n) v.y = counts[base + 1];
        if (base + 2 < n) v.z = counts[base + 2];
        if (base + 3 < n) v.w = counts[base + 3];
    }
    int tsum = v.x + v.y + v.z + v.w;
    s[t] = tsum;
    __syncthreads();
#pragma unroll
    for (int off = 1; off < 256; off <<= 1) {
        int val = (t >= off) ? s[t - off] : 0;
        __syncthreads();
        s[t] += val;
        __syncthreads();
    }
    if (t == 255) blockSums[blockIdx.x] = s[255];
    int e0 = s[t] - tsum;
    int e1 = e0 + v.x;
    int e2 = e1 + v.y;
    int e3 = e2 + v.z;
    if (base + 0 < n) excl[base + 0] = e0;
    if (base + 1 < n) excl[base + 1] = e1;
    if (base + 2 < n) excl[base + 2] = e2;
    if (base + 3 < n) excl[base + 3] = e3;
}

__global__ __launch_bounds__(256) void scan_phase2(int* blockSums, int nb)
{
    __shared__ int s[256];
    int t = threadIdx.x;
    int v = (t < nb) ? blockSums[t] : 0;
    s[t] = v;
    __syncthreads();
#pragma unroll
    for (int off = 1; off < 256; off <<= 1) {
        int val = (t >= off) ? s[t - off] : 0;
        __syncthreads();
        s[t] += val;
        __syncthreads();
    }
    if (t < nb) blockSums[t] = s[t] - v;
}

__global__ __launch_bounds__(256) void scan_phase3(
    int* __restrict__ offsets, const int* __restrict__ blockSums,
    int* __restrict__ cursor, int n)
{
    int i = blockIdx.x * 256 + threadIdx.x;
    if (i >= n) return;
    int o = offsets[i] + blockSums[i >> 10];
    offsets[i] = o;
    cursor[i]  = o;
}

__global__ __launch_bounds__(256) void scatter_kernel(
    const int* __restrict__ row, const int* __restrict__ col,
    const float* __restrict__ val, int* __restrict__ cursor,
    uint2* __restrict__ edata, int E)
{
    int e = blockIdx.x * 256 + threadIdx.x;
    if (e >= E) return;
    int r = row[e];
    int pos = atomicAdd(&cursor[r], 1);
    uint2 d;
    d.x = (unsigned)col[e];
    d.y = __float_as_uint(val[e]);
    edata[pos] = d;
}

// ---------------------------------------------------------------------------
// pull SpMM: one wave per row, lane = emb dim, 8-deep ILP, bf16 emb table
// ---------------------------------------------------------------------------
__global__ __launch_bounds__(256) void pull_kernel(
    const int* __restrict__ offsets, const int* __restrict__ counts,
    const uint2* __restrict__ edata, const unsigned short* __restrict__ embb,
    unsigned short* __restrict__ xb, int Nn)
{
    int r    = blockIdx.x * 4 + (threadIdx.x >> 6);
    int lane = threadIdx.x & 63;
    if (r >= Nn) return;
    int beg = offsets[r];
    int cnt = counts[r];
    float acc = 0.f;
    for (int i = 0; i < cnt; i += 8) {
        uint2 ed[8];
#pragma unroll
        for (int j = 0; j < 8; ++j) {
            int idx = i + j;
            idx = (idx < cnt) ? idx : (cnt - 1);
            ed[j] = edata[beg + idx];
        }
        float g[8];
#pragma unroll
        for (int j = 0; j < 8; ++j)
            g[j] = bf2f(embb[(size_t)ed[j].x * EMB + lane]);
#pragma unroll
        for (int j = 0; j < 8; ++j) {
            float v = (i + j < cnt) ? __uint_as_float(ed[j].y) : 0.f;
            acc += v * g[j];
        }
    }
    xb[(size_t)r * EMB + lane] = f2bf(acc);
}

// ---------------------------------------------------------------------------
// fused 3-layer MLP, B-operand direct from global (fragment-major, L2-hot):
// out = relu(relu(x@W0)@W1)@W2
// block = 256 thr (4 waves), 64 rows, full 256-col width.
// LDS: H only (64 x 256 bf16 = 32KB), XOR-swizzled (byte ^= (row&7)<<4).
// No barriers inside K-loops (H read-only per phase); 3 barriers total.
// ---------------------------------------------------------------------------
__global__ __launch_bounds__(256) void mlp_fused(
    const unsigned short* __restrict__ xb,   // [M][64]  bf16
    const unsigned short* __restrict__ W0f,  // frag-major, KC=2
    const unsigned short* __restrict__ W1f,  // frag-major, KC=8
    const unsigned short* __restrict__ W2f,  // frag-major, KC=8
    float* __restrict__ out, int M)
{
    __shared__ unsigned short H[64 * 256];   // 32 KB, rows of 512B, swizzled

    const int t    = threadIdx.x;
    const int lane = t & 63;
    const int w    = t >> 6;
    const int lr   = lane & 15;
    const int kg   = lane >> 4;
    const int row0 = blockIdx.x * 64;
    char* Hb = (char*)H;

    // swizzled byte offset into H
#define HOFF(row, bytecol) ((((row) * 512) + (bytecol)) ^ (((row) & 7) << 4))

    // ---------------- phase 1: h0 = relu(x @ W0), K = 64 ----------------
    short8_t ax[2][4];
#pragma unroll
    for (int kc = 0; kc < 2; ++kc)
#pragma unroll
        for (int m = 0; m < 4; ++m) {
            int gr = row0 + m * 16 + lr;
            ax[kc][m] = *(const short8_t*)(xb + (size_t)(gr < M ? gr : 0) * EMB
                                           + kc * 32 + kg * 8);
        }
    f32x4 acc[4][4] = {};
#pragma unroll
    for (int kc = 0; kc < 2; ++kc) {
        short8_t b[4];
#pragma unroll
        for (int n = 0; n < 4; ++n)
            b[n] = *(const short8_t*)&W0f[(size_t)(((w * 4 + n) * 2 + kc) * 64 + lane) * 8];
#pragma unroll
        for (int m = 0; m < 4; ++m)
#pragma unroll
            for (int n = 0; n < 4; ++n)
                acc[m][n] = __builtin_amdgcn_mfma_f32_16x16x32_bf16(
                    ax[kc][m], b[n], acc[m][n], 0, 0, 0);
    }
    // write h0 -> H (relu). D map: col = lane&15, row = (lane>>4)*4 + reg
#pragma unroll
    for (int m = 0; m < 4; ++m)
#pragma unroll
        for (int r = 0; r < 4; ++r)
#pragma unroll
            for (int n = 0; n < 4; ++n)
                *(unsigned short*)(Hb + HOFF(m * 16 + kg * 4 + r,
                                             (w * 64 + n * 16 + lr) * 2)) =
                    f2bf(fmaxf(acc[m][n][r], 0.f));
    __syncthreads();

    // ---------------- phase 2: h1 = relu(h0 @ W1), K = 256 ----------------
    f32x4 acc2[4][4] = {};
#pragma unroll
    for (int kc = 0; kc < 8; ++kc) {
        short8_t a[4], b[4];
#pragma unroll
        for (int n = 0; n < 4; ++n)
            b[n] = *(const short8_t*)&W1f[(size_t)(((w * 4 + n) * 8 + kc) * 64 + lane) * 8];
#pragma unroll
        for (int m = 0; m < 4; ++m)
            a[m] = *(const short8_t*)(Hb + HOFF(m * 16 + lr, kc * 64 + kg * 16));
#pragma unroll
        for (int m = 0; m < 4; ++m)
#pragma unroll
            for (int n = 0; n < 4; ++n)
                acc2[m][n] = __builtin_amdgcn_mfma_f32_16x16x32_bf16(
                    a[m], b[n], acc2[m][n], 0, 0, 0);
    }
    __syncthreads();   // all h0 reads done
    // write h1 -> H in place
#pragma unroll
    for (int m = 0; m < 4; ++m)
#pragma unroll
        for (int r = 0; r < 4; ++r)
#pragma unroll
            for (int n = 0; n < 4; ++n)
                *(unsigned short*)(Hb + HOFF(m * 16 + kg * 4 + r,
                                             (w * 64 + n * 16 + lr) * 2)) =
                    f2bf(fmaxf(acc2[m][n][r], 0.f));
    __syncthreads();   // h1 visible

    // ---------------- phase 3: out = h1 @ W2, K = 256 ----------------
    f32x4 acc3[4][4] = {};
#pragma unroll
    for (int kc = 0; kc < 8; ++kc) {
        short8_t a[4], b[4];
#pragma unroll
        for (int n = 0; n < 4; ++n)
            b[n] = *(const short8_t*)&W2f[(size_t)(((w * 4 + n) * 8 + kc) * 64 + lane) * 8];
#pragma unroll
        for (int m = 0; m < 4; ++m)
            a[m] = *(const short8_t*)(Hb + HOFF(m * 16 + lr, kc * 64 + kg * 16));
#pragma unroll
        for (int m = 0; m < 4; ++m)
#pragma unroll
            for (int n = 0; n < 4; ++n)
                acc3[m][n] = __builtin_amdgcn_mfma_f32_16x16x32_bf16(
                    a[m], b[n], acc3[m][n], 0, 0, 0);
    }
    // epilogue: fp32 out
#pragma unroll
    for (int m = 0; m < 4; ++m)
#pragma unroll
        for (int r = 0; r < 4; ++r) {
            int gr = row0 + m * 16 + kg * 4 + r;
            if (gr < M)
#pragma unroll
                for (int n = 0; n < 4; ++n)
                    out[(size_t)gr * HID + w * 64 + n * 16 + lr] = acc3[m][n][r];
        }
#undef HOFF
}

// ---------------------------------------------------------------------------
// fallback path kernels (ws too small): atomic scatter SpMM + fp32 GEMM
// ---------------------------------------------------------------------------
__global__ __launch_bounds__(256) void spmm_kernel(
    const int* __restrict__ row, const int* __restrict__ col,
    const float* __restrict__ val, const float* __restrict__ emb,
    float* __restrict__ x, int E)
{
    int gid  = blockIdx.x * blockDim.x + threadIdx.x;
    int e    = gid >> 6;
    int lane = gid & 63;
    if (e >= E) return;
    unsafeAtomicAdd(&x[(size_t)row[e] * EMB + lane],
                    val[e] * emb[(size_t)col[e] * EMB + lane]);
}

template<int K, bool RELU>
__global__ __launch_bounds__(256) void gemm_f32(
    const float* A, const float* __restrict__ B, float* C, int M)
{
    __shared__ float As[64][17];
    __shared__ float Bs[16][256];

    const int t    = threadIdx.x;
    const int tn   = t & 15;
    const int row0 = blockIdx.x * 64;
    const int sk = t & 15;
    const int sm = (t >> 4) * 4;

    float acc[4][16];
#pragma unroll
    for (int i = 0; i < 4; ++i)
#pragma unroll
        for (int j = 0; j < 16; ++j) acc[i][j] = 0.f;

    const int mB = ((t & 63) >> 4) * 4;
    const int wq = t >> 6;
    const int myM = (wq * 16) + mB;

    for (int k0 = 0; k0 < K; k0 += 16) {
        __syncthreads();
#pragma unroll
        for (int i = 0; i < 4; ++i) {
            int m  = sm + i;
            int gr = row0 + m;
            As[m][sk] = (gr < M) ? A[(size_t)gr * K + k0 + sk] : 0.f;
        }
#pragma unroll
        for (int r = 0; r < 16; ++r)
            Bs[r][t] = B[(size_t)(k0 + r) * 256 + t];
        __syncthreads();

#pragma unroll
        for (int kk = 0; kk < 16; ++kk) {
            float a0 = As[myM + 0][kk];
            float a1 = As[myM + 1][kk];
            float a2 = As[myM + 2][kk];
            float a3 = As[myM + 3][kk];
            float4 b[4];
#pragma unroll
            for (int j = 0; j < 4; ++j)
                b[j] = *(const float4*)&Bs[kk][tn * 4 + j * 64];
#pragma unroll
            for (int j = 0; j < 4; ++j) {
                acc[0][j*4+0] += a0 * b[j].x;  acc[0][j*4+1] += a0 * b[j].y;
                acc[0][j*4+2] += a0 * b[j].z;  acc[0][j*4+3] += a0 * b[j].w;
                acc[1][j*4+0] += a1 * b[j].x;  acc[1][j*4+1] += a1 * b[j].y;
                acc[1][j*4+2] += a1 * b[j].z;  acc[1][j*4+3] += a1 * b[j].w;
                acc[2][j*4+0] += a2 * b[j].x;  acc[2][j*4+1] += a2 * b[j].y;
                acc[2][j*4+2] += a2 * b[j].z;  acc[2][j*4+3] += a2 * b[j].w;
                acc[3][j*4+0] += a3 * b[j].x;  acc[3][j*4+1] += a3 * b[j].y;
                acc[3][j*4+2] += a3 * b[j].z;  acc[3][j*4+3] += a3 * b[j].w;
            }
        }
    }

#pragma unroll
    for (int i = 0; i < 4; ++i) {
        int gr = row0 + myM + i;
        if (gr < M) {
#pragma unroll
            for (int j = 0; j < 4; ++j) {
                float4 o;
                o.x = acc[i][j*4+0]; o.y = acc[i][j*4+1];
                o.z = acc[i][j*4+2]; o.w = acc[i][j*4+3];
                if (RELU) {
                    o.x = fmaxf(o.x, 0.f); o.y = fmaxf(o.y, 0.f);
                    o.z = fmaxf(o.z, 0.f); o.w = fmaxf(o.w, 0.f);
                }
                *(float4*)&C[(size_t)gr * 256 + tn * 4 + j * 64] = o;
            }
        }
    }
}

extern "C" void kernel_launch(void* const* d_in, const int* in_sizes, int n_in,
                              void* d_out, int out_size, void* d_ws, size_t ws_size,
                              hipStream_t stream)
{
    const int*   row = (const int*)d_in[0];
    const int*   col = (const int*)d_in[1];
    const float* val = (const float*)d_in[2];
    const float* emb = (const float*)d_in[3];
    const float* W0  = (const float*)d_in[4];
    const float* W1  = (const float*)d_in[5];
    const float* W2  = (const float*)d_in[6];
    float* out = (float*)d_out;

    const int E = in_sizes[0];
    const int M = in_sizes[3] / EMB;   // num nodes

    char* ws = (char*)d_ws;

    // ---- ws layout (256B-aligned regions) ----
    size_t off = 0;
    auto alloc = [&](size_t bytes) { size_t o = off; off = (off + bytes + 255) & ~(size_t)255; return o; };
    const size_t off_counts = alloc((size_t)M * 4);
    const size_t off_offs   = alloc((size_t)M * 4);
    const size_t off_cursor = alloc((size_t)M * 4);
    const size_t off_bsums  = alloc(1024);
    const size_t off_edata  = alloc((size_t)E * 8);
    const size_t off_embb   = alloc((size_t)M * EMB * 2);
    const size_t off_xb     = alloc((size_t)M * EMB * 2);
    const size_t off_w0     = alloc((size_t)EMB * HID * 2);
    const size_t off_w1     = alloc((size_t)HID * HID * 2);
    const size_t off_w2     = alloc((size_t)HID * HID * 2);
    const size_t need       = off;

    int gblocks = (M + 63) / 64;

    if (ws_size >= need) {
        int*   counts = (int*)(ws + off_counts);
        int*   offs   = (int*)(ws + off_offs);
        int*   cursor = (int*)(ws + off_cursor);
        int*   bsums  = (int*)(ws + off_bsums);
        uint2* edata  = (uint2*)(ws + off_edata);
        unsigned short* embb = (unsigned short*)(ws + off_embb);
        unsigned short* xb  = (unsigned short*)(ws + off_xb);
        unsigned short* W0f = (unsigned short*)(ws + off_w0);
        unsigned short* W1f = (unsigned short*)(ws + off_w1);
        unsigned short* W2f = (unsigned short*)(ws + off_w2);

        // fused prep: zero counts + emb->bf16 + weight fragment-major pack
        int zb = (M / 4 + 255) / 256;
        int cb = ((M * EMB) / 4 + 255) / 256;
        int prep_blocks = zb + cb + 8 + 32 + 32;
        prep_kernel<<<prep_blocks, 256, 0, stream>>>(
            emb, W0, W1, W2, counts, embb, W0f, W1f, W2f, M, zb, cb);

        // CSR build
        hist_kernel<<<(E / 4 + 255) / 256, 256, 0, stream>>>(row, counts, E);
        int nb = (M + 1023) / 1024;
        scan_phase1<<<nb, 256, 0, stream>>>(counts, offs, bsums, M);
        scan_phase2<<<1, 256, 0, stream>>>(bsums, nb);
        scan_phase3<<<(M + 255) / 256, 256, 0, stream>>>(offs, bsums, cursor, M);
        scatter_kernel<<<(E + 255) / 256, 256, 0, stream>>>(row, col, val, cursor, edata, E);

        // pull SpMM -> xb (bf16)
        pull_kernel<<<(M + 3) / 4, 256, 0, stream>>>(offs, counts, edata, embb, xb, M);

        // fused 3-layer MLP -> out
        mlp_fused<<<gblocks, 256, 0, stream>>>(xb, W0f, W1f, W2f, out, M);
    } else {
        // fp32 fallback (ws too small): atomic scatter SpMM + fp32 GEMMs
        float* x = (float*)ws;
        (void)hipMemsetAsync(x, 0, (size_t)M * EMB * sizeof(float), stream);
        spmm_kernel<<<(E + 3) / 4, 256, 0, stream>>>(row, col, val, emb, x, E);
        gemm_f32<EMB, true ><<<gblocks, 256, 0, stream>>>(x,   W0, out, M);
        gemm_f32<HID, true ><<<gblocks, 256, 0, stream>>>(out, W1, out, M);
        gemm_f32<HID, false><<<gblocks, 256, 0, stream>>>(out, W2, out, M);
    }
}

// Round 12
// 195.934 us; speedup vs baseline: 3.1535x; 1.0257x over previous
//
#include <hip/hip_runtime.h>
#include <hip/hip_bf16.h>

#define EMB 64
#define HID 256

typedef __attribute__((ext_vector_type(8))) short short8_t;   // 8 bf16 = 4 VGPRs
typedef __attribute__((ext_vector_type(4))) float f32x4;

// fp32 -> bf16 bits, round-to-nearest-even (matches HW conversion)
__device__ __forceinline__ unsigned short f2bf(float f)
{
    union { float f; unsigned int u; } c; c.f = f;
    unsigned int u = c.u;
    u += 0x7fffu + ((u >> 16) & 1u);
    return (unsigned short)(u >> 16);
}
__device__ __forceinline__ float bf2f(unsigned short b)
{
    union { unsigned int u; float f; } c; c.u = ((unsigned int)b) << 16;
    return c.f;
}

// ---------------------------------------------------------------------------
// prep: fused {zero counts | emb->bf16 | W0/W1/W2 -> MFMA fragment-major bf16}
// Wf[((nt*KC + kc)*64 + lane)*8 + j] = W[kc*32 + kg*8 + j][nt*16 + lr]
// ---------------------------------------------------------------------------
__global__ __launch_bounds__(256) void prep_kernel(
    const float* __restrict__ emb, const float* __restrict__ W0,
    const float* __restrict__ W1, const float* __restrict__ W2,
    int* __restrict__ counts, unsigned short* __restrict__ embb,
    unsigned short* __restrict__ W0f, unsigned short* __restrict__ W1f,
    unsigned short* __restrict__ W2f, int M, int zb, int cb)
{
    int b = blockIdx.x;
    if (b < zb) {                              // zero counts[M]
        int idx = (b * 256 + threadIdx.x) * 4;
        if (idx + 3 < M) {
            int4 z; z.x = 0; z.y = 0; z.z = 0; z.w = 0;
            *(int4*)&counts[idx] = z;
        } else {
            for (int i = idx; i < M; ++i) counts[i] = 0;
        }
        return;
    }
    b -= zb;
    if (b < cb) {                              // emb fp32 -> bf16
        int idx = (b * 256 + threadIdx.x) * 4;
        if (idx + 3 < M * EMB) {
            float4 v = *(const float4*)&emb[idx];
            ushort4 o;
            o.x = f2bf(v.x); o.y = f2bf(v.y); o.z = f2bf(v.z); o.w = f2bf(v.w);
            *(ushort4*)&embb[idx] = o;
        }
        return;
    }
    b -= cb;
    if (b < 8) {                               // W0f: 16 nt x 2 kc x 64 lanes
        int i    = b * 256 + threadIdx.x;
        int lane = i & 63;
        int kc   = (i >> 6) & 1;
        int nt   = i >> 7;
        int lr   = lane & 15, kg = lane >> 4;
        unsigned short tmp[8];
#pragma unroll
        for (int j = 0; j < 8; ++j)
            tmp[j] = f2bf(W0[(kc * 32 + kg * 8 + j) * HID + nt * 16 + lr]);
        *(short8_t*)&W0f[(size_t)i * 8] = *(short8_t*)tmp;
        return;
    }
    b -= 8;
    if (b < 32) {                              // W1f: 16 nt x 8 kc x 64 lanes
        int i    = b * 256 + threadIdx.x;
        int lane = i & 63;
        int kc   = (i >> 6) & 7;
        int nt   = i >> 9;
        int lr   = lane & 15, kg = lane >> 4;
        unsigned short tmp[8];
#pragma unroll
        for (int j = 0; j < 8; ++j)
            tmp[j] = f2bf(W1[(kc * 32 + kg * 8 + j) * HID + nt * 16 + lr]);
        *(short8_t*)&W1f[(size_t)i * 8] = *(short8_t*)tmp;
        return;
    }
    b -= 32;
    {                                          // W2f
        int i    = b * 256 + threadIdx.x;
        int lane = i & 63;
        int kc   = (i >> 6) & 7;
        int nt   = i >> 9;
        int lr   = lane & 15, kg = lane >> 4;
        unsigned short tmp[8];
#pragma unroll
        for (int j = 0; j < 8; ++j)
            tmp[j] = f2bf(W2[(kc * 32 + kg * 8 + j) * HID + nt * 16 + lr]);
        *(short8_t*)&W2f[(size_t)i * 8] = *(short8_t*)tmp;
    }
}

// ---------------------------------------------------------------------------
// CSR build: histogram -> exclusive scan -> bucket scatter
// ---------------------------------------------------------------------------
__global__ __launch_bounds__(256) void hist_kernel(
    const int* __restrict__ row, int* __restrict__ counts, int E)
{
    int base = (blockIdx.x * 256 + threadIdx.x) * 4;
    if (base + 3 < E) {
        int4 r4 = *(const int4*)&row[base];
        atomicAdd(&counts[r4.x], 1);
        atomicAdd(&counts[r4.y], 1);
        atomicAdd(&counts[r4.z], 1);
        atomicAdd(&counts[r4.w], 1);
    } else {
        for (int i = base; i < E; ++i) atomicAdd(&counts[row[i]], 1);
    }
}

__global__ __launch_bounds__(256) void scan_phase1(
    const int* __restrict__ counts, int* __restrict__ excl,
    int* __restrict__ blockSums, int n)
{
    __shared__ int s[256];
    int t = threadIdx.x;
    int base = blockIdx.x * 1024 + t * 4;
    int4 v = {0, 0, 0, 0};
    if (base + 3 < n) {
        v = *(const int4*)&counts[base];
    } else {
        if (base + 0 < n) v.x = counts[base + 0];
        if (base + 1 < n) v.y = counts[base + 1];
        if (base + 2 < n) v.z = counts[base + 2];
        if (base + 3 < n) v.w = counts[base + 3];
    }
    int tsum = v.x + v.y + v.z + v.w;
    s[t] = tsum;
    __syncthreads();
#pragma unroll
    for (int off = 1; off < 256; off <<= 1) {
        int val = (t >= off) ? s[t - off] : 0;
        __syncthreads();
        s[t] += val;
        __syncthreads();
    }
    if (t == 255) blockSums[blockIdx.x] = s[255];
    int e0 = s[t] - tsum;
    int e1 = e0 + v.x;
    int e2 = e1 + v.y;
    int e3 = e2 + v.z;
    if (base + 0 < n) excl[base + 0] = e0;
    if (base + 1 < n) excl[base + 1] = e1;
    if (base + 2 < n) excl[base + 2] = e2;
    if (base + 3 < n) excl[base + 3] = e3;
}

__global__ __launch_bounds__(256) void scan_phase2(int* blockSums, int nb)
{
    __shared__ int s[256];
    int t = threadIdx.x;
    int v = (t < nb) ? blockSums[t] : 0;
    s[t] = v;
    __syncthreads();
#pragma unroll
    for (int off = 1; off < 256; off <<= 1) {
        int val = (t >= off) ? s[t - off] : 0;
        __syncthreads();
        s[t] += val;
        __syncthreads();
    }
    if (t < nb) blockSums[t] = s[t] - v;
}

__global__ __launch_bounds__(256) void scan_phase3(
    int* __restrict__ offsets, const int* __restrict__ blockSums,
    int* __restrict__ cursor, int n)
{
    int i = blockIdx.x * 256 + threadIdx.x;
    if (i >= n) return;
    int o = offsets[i] + blockSums[i >> 10];
    offsets[i] = o;
    cursor[i]  = o;
}

__global__ __launch_bounds__(256) void scatter_kernel(
    const int* __restrict__ row, const int* __restrict__ col,
    const float* __restrict__ val, int* __restrict__ cursor,
    uint2* __restrict__ edata, int E)
{
    int e = blockIdx.x * 256 + threadIdx.x;
    if (e >= E) return;
    int r = row[e];
    int pos = atomicAdd(&cursor[r], 1);
    uint2 d;
    d.x = (unsigned)col[e];
    d.y = __float_as_uint(val[e]);
    edata[pos] = d;
}

// ---------------------------------------------------------------------------
// pull SpMM v3: grid-stride, ~8 rows per wave, next-row (beg,cnt) prefetch,
// 8-deep ILP gathers from bf16 emb table.
// ---------------------------------------------------------------------------
#define ROWS_PER_WAVE 8
__global__ __launch_bounds__(256) void pull_kernel(
    const int* __restrict__ offsets, const int* __restrict__ counts,
    const uint2* __restrict__ edata, const unsigned short* __restrict__ embb,
    unsigned short* __restrict__ xb, int Nn)
{
    const int nw   = gridDim.x * 4;                  // total waves
    const int wid  = blockIdx.x * 4 + (threadIdx.x >> 6);
    const int lane = threadIdx.x & 63;
    if (wid >= Nn) return;

    int beg = offsets[wid];
    int cnt = counts[wid];
    for (int r = wid; r < Nn; r += nw) {
        int rn = r + nw;
        int begN = 0, cntN = 0;
        if (rn < Nn) { begN = offsets[rn]; cntN = counts[rn]; }

        float acc = 0.f;
        for (int i = 0; i < cnt; i += 8) {
            uint2 ed[8];
#pragma unroll
            for (int j = 0; j < 8; ++j) {
                int idx = i + j;
                idx = (idx < cnt) ? idx : (cnt - 1);
                ed[j] = edata[beg + idx];
            }
            float g[8];
#pragma unroll
            for (int j = 0; j < 8; ++j)
                g[j] = bf2f(embb[(size_t)ed[j].x * EMB + lane]);
#pragma unroll
            for (int j = 0; j < 8; ++j) {
                float v = (i + j < cnt) ? __uint_as_float(ed[j].y) : 0.f;
                acc += v * g[j];
            }
        }
        xb[(size_t)r * EMB + lane] = f2bf(acc);
        beg = begN; cnt = cntN;
    }
}

// ---------------------------------------------------------------------------
// fused 3-layer MLP, BM=32, B-operand direct from global (fragment-major):
// out = relu(relu(x@W0)@W1)@W2
// block = 256 thr (4 waves), 32 rows, full 256-col width; wave w owns cols
// [w*64, w*64+64), 2 m-tiles x 4 n-tiles. LDS: H = 32x256 bf16 (16KB),
// XOR-swizzled; reused as fp32 staging for the vectorized epilogue.
// ---------------------------------------------------------------------------
__global__ __launch_bounds__(256) void mlp_fused(
    const unsigned short* __restrict__ xb,   // [M][64]  bf16
    const unsigned short* __restrict__ W0f,  // frag-major, KC=2
    const unsigned short* __restrict__ W1f,  // frag-major, KC=8
    const unsigned short* __restrict__ W2f,  // frag-major, KC=8
    float* __restrict__ out, int M)
{
    __shared__ unsigned short H[32 * 256];   // 16 KB

    const int t    = threadIdx.x;
    const int lane = t & 63;
    const int w    = t >> 6;
    const int lr   = lane & 15;
    const int kg   = lane >> 4;
    const int row0 = blockIdx.x * 32;
    char* Hb = (char*)H;

#define HOFF(row, bytecol) ((((row) * 512) + (bytecol)) ^ (((row) & 7) << 4))

    // ---------------- phase 1: h0 = relu(x @ W0), K = 64 ----------------
    short8_t ax[2][2];
#pragma unroll
    for (int kc = 0; kc < 2; ++kc)
#pragma unroll
        for (int m = 0; m < 2; ++m) {
            int gr = row0 + m * 16 + lr;
            ax[kc][m] = *(const short8_t*)(xb + (size_t)(gr < M ? gr : 0) * EMB
                                           + kc * 32 + kg * 8);
        }
    f32x4 acc[2][4] = {};
#pragma unroll
    for (int kc = 0; kc < 2; ++kc) {
        short8_t b[4];
#pragma unroll
        for (int n = 0; n < 4; ++n)
            b[n] = *(const short8_t*)&W0f[(size_t)(((w * 4 + n) * 2 + kc) * 64 + lane) * 8];
#pragma unroll
        for (int m = 0; m < 2; ++m)
#pragma unroll
            for (int n = 0; n < 4; ++n)
                acc[m][n] = __builtin_amdgcn_mfma_f32_16x16x32_bf16(
                    ax[kc][m], b[n], acc[m][n], 0, 0, 0);
    }
#pragma unroll
    for (int m = 0; m < 2; ++m)
#pragma unroll
        for (int r = 0; r < 4; ++r)
#pragma unroll
            for (int n = 0; n < 4; ++n)
                *(unsigned short*)(Hb + HOFF(m * 16 + kg * 4 + r,
                                             (w * 64 + n * 16 + lr) * 2)) =
                    f2bf(fmaxf(acc[m][n][r], 0.f));
    __syncthreads();

    // ---------------- phase 2: h1 = relu(h0 @ W1), K = 256 ----------------
    f32x4 acc2[2][4] = {};
#pragma unroll
    for (int kc = 0; kc < 8; ++kc) {
        short8_t a[2], b[4];
#pragma unroll
        for (int n = 0; n < 4; ++n)
            b[n] = *(const short8_t*)&W1f[(size_t)(((w * 4 + n) * 8 + kc) * 64 + lane) * 8];
#pragma unroll
        for (int m = 0; m < 2; ++m)
            a[m] = *(const short8_t*)(Hb + HOFF(m * 16 + lr, kc * 64 + kg * 16));
#pragma unroll
        for (int m = 0; m < 2; ++m)
#pragma unroll
            for (int n = 0; n < 4; ++n)
                acc2[m][n] = __builtin_amdgcn_mfma_f32_16x16x32_bf16(
                    a[m], b[n], acc2[m][n], 0, 0, 0);
    }
    __syncthreads();   // all h0 reads done
#pragma unroll
    for (int m = 0; m < 2; ++m)
#pragma unroll
        for (int r = 0; r < 4; ++r)
#pragma unroll
            for (int n = 0; n < 4; ++n)
                *(unsigned short*)(Hb + HOFF(m * 16 + kg * 4 + r,
                                             (w * 64 + n * 16 + lr) * 2)) =
                    f2bf(fmaxf(acc2[m][n][r], 0.f));
    __syncthreads();   // h1 visible

    // ---------------- phase 3: out = h1 @ W2, K = 256 ----------------
    f32x4 acc3[2][4] = {};
#pragma unroll
    for (int kc = 0; kc < 8; ++kc) {
        short8_t a[2], b[4];
#pragma unroll
        for (int n = 0; n < 4; ++n)
            b[n] = *(const short8_t*)&W2f[(size_t)(((w * 4 + n) * 8 + kc) * 64 + lane) * 8];
#pragma unroll
        for (int m = 0; m < 2; ++m)
            a[m] = *(const short8_t*)(Hb + HOFF(m * 16 + lr, kc * 64 + kg * 16));
#pragma unroll
        for (int m = 0; m < 2; ++m)
#pragma unroll
            for (int n = 0; n < 4; ++n)
                acc3[m][n] = __builtin_amdgcn_mfma_f32_16x16x32_bf16(
                    a[m], b[n], acc3[m][n], 0, 0, 0);
    }
    __syncthreads();   // phase-3 H reads complete; H free for staging

    // ------------- epilogue: LDS-bounce -> coalesced dwordx4 stores -------------
    float* Hf = (float*)H;            // per-wave private 4KB region: w*1024 floats
#pragma unroll
    for (int m = 0; m < 2; ++m) {
#pragma unroll
        for (int n = 0; n < 4; ++n)
#pragma unroll
            for (int r = 0; r < 4; ++r)
                Hf[w * 1024 + (kg * 4 + r) * 64 + n * 16 + lr] = acc3[m][n][r];
        // read back row-major: 4 passes of 4 rows x 16 float4
#pragma unroll
        for (int p = 0; p < 4; ++p) {
            int rl = (lane >> 4) + p * 4;                   // 0..15
            f32x4 v = *(const f32x4*)&Hf[w * 1024 + rl * 64 + (lane & 15) * 4];
            int gr = row0 + m * 16 + rl;
            if (gr < M)
                *(f32x4*)&out[(size_t)gr * HID + w * 64 + (lane & 15) * 4] = v;
        }
    }
#undef HOFF
}

// ---------------------------------------------------------------------------
// fallback path kernels (ws too small): atomic scatter SpMM + fp32 GEMM
// ---------------------------------------------------------------------------
__global__ __launch_bounds__(256) void spmm_kernel(
    const int* __restrict__ row, const int* __restrict__ col,
    const float* __restrict__ val, const float* __restrict__ emb,
    float* __restrict__ x, int E)
{
    int gid  = blockIdx.x * blockDim.x + threadIdx.x;
    int e    = gid >> 6;
    int lane = gid & 63;
    if (e >= E) return;
    unsafeAtomicAdd(&x[(size_t)row[e] * EMB + lane],
                    val[e] * emb[(size_t)col[e] * EMB + lane]);
}

template<int K, bool RELU>
__global__ __launch_bounds__(256) void gemm_f32(
    const float* A, const float* __restrict__ B, float* C, int M)
{
    __shared__ float As[64][17];
    __shared__ float Bs[16][256];

    const int t    = threadIdx.x;
    const int tn   = t & 15;
    const int row0 = blockIdx.x * 64;
    const int sk = t & 15;
    const int sm = (t >> 4) * 4;

    float acc[4][16];
#pragma unroll
    for (int i = 0; i < 4; ++i)
#pragma unroll
        for (int j = 0; j < 16; ++j) acc[i][j] = 0.f;

    const int mB = ((t & 63) >> 4) * 4;
    const int wq = t >> 6;
    const int myM = (wq * 16) + mB;

    for (int k0 = 0; k0 < K; k0 += 16) {
        __syncthreads();
#pragma unroll
        for (int i = 0; i < 4; ++i) {
            int m  = sm + i;
            int gr = row0 + m;
            As[m][sk] = (gr < M) ? A[(size_t)gr * K + k0 + sk] : 0.f;
        }
#pragma unroll
        for (int r = 0; r < 16; ++r)
            Bs[r][t] = B[(size_t)(k0 + r) * 256 + t];
        __syncthreads();

#pragma unroll
        for (int kk = 0; kk < 16; ++kk) {
            float a0 = As[myM + 0][kk];
            float a1 = As[myM + 1][kk];
            float a2 = As[myM + 2][kk];
            float a3 = As[myM + 3][kk];
            float4 b[4];
#pragma unroll
            for (int j = 0; j < 4; ++j)
                b[j] = *(const float4*)&Bs[kk][tn * 4 + j * 64];
#pragma unroll
            for (int j = 0; j < 4; ++j) {
                acc[0][j*4+0] += a0 * b[j].x;  acc[0][j*4+1] += a0 * b[j].y;
                acc[0][j*4+2] += a0 * b[j].z;  acc[0][j*4+3] += a0 * b[j].w;
                acc[1][j*4+0] += a1 * b[j].x;  acc[1][j*4+1] += a1 * b[j].y;
                acc[1][j*4+2] += a1 * b[j].z;  acc[1][j*4+3] += a1 * b[j].w;
                acc[2][j*4+0] += a2 * b[j].x;  acc[2][j*4+1] += a2 * b[j].y;
                acc[2][j*4+2] += a2 * b[j].z;  acc[2][j*4+3] += a2 * b[j].w;
                acc[3][j*4+0] += a3 * b[j].x;  acc[3][j*4+1] += a3 * b[j].y;
                acc[3][j*4+2] += a3 * b[j].z;  acc[3][j*4+3] += a3 * b[j].w;
            }
        }
    }

#pragma unroll
    for (int i = 0; i < 4; ++i) {
        int gr = row0 + myM + i;
        if (gr < M) {
#pragma unroll
            for (int j = 0; j < 4; ++j) {
                float4 o;
                o.x = acc[i][j*4+0]; o.y = acc[i][j*4+1];
                o.z = acc[i][j*4+2]; o.w = acc[i][j*4+3];
                if (RELU) {
                    o.x = fmaxf(o.x, 0.f); o.y = fmaxf(o.y, 0.f);
                    o.z = fmaxf(o.z, 0.f); o.w = fmaxf(o.w, 0.f);
                }
                *(float4*)&C[(size_t)gr * 256 + tn * 4 + j * 64] = o;
            }
        }
    }
}

extern "C" void kernel_launch(void* const* d_in, const int* in_sizes, int n_in,
                              void* d_out, int out_size, void* d_ws, size_t ws_size,
                              hipStream_t stream)
{
    const int*   row = (const int*)d_in[0];
    const int*   col = (const int*)d_in[1];
    const float* val = (const float*)d_in[2];
    const float* emb = (const float*)d_in[3];
    const float* W0  = (const float*)d_in[4];
    const float* W1  = (const float*)d_in[5];
    const float* W2  = (const float*)d_in[6];
    float* out = (float*)d_out;

    const int E = in_sizes[0];
    const int M = in_sizes[3] / EMB;   // num nodes

    char* ws = (char*)d_ws;

    // ---- ws layout (256B-aligned regions) ----
    size_t off = 0;
    auto alloc = [&](size_t bytes) { size_t o = off; off = (off + bytes + 255) & ~(size_t)255; return o; };
    const size_t off_counts = alloc((size_t)M * 4);
    const size_t off_offs   = alloc((size_t)M * 4);
    const size_t off_cursor = alloc((size_t)M * 4);
    const size_t off_bsums  = alloc(1024);
    const size_t off_edata  = alloc((size_t)E * 8);
    const size_t off_embb   = alloc((size_t)M * EMB * 2);
    const size_t off_xb     = alloc((size_t)M * EMB * 2);
    const size_t off_w0     = alloc((size_t)EMB * HID * 2);
    const size_t off_w1     = alloc((size_t)HID * HID * 2);
    const size_t off_w2     = alloc((size_t)HID * HID * 2);
    const size_t need       = off;

    if (ws_size >= need) {
        int*   counts = (int*)(ws + off_counts);
        int*   offs   = (int*)(ws + off_offs);
        int*   cursor = (int*)(ws + off_cursor);
        int*   bsums  = (int*)(ws + off_bsums);
        uint2* edata  = (uint2*)(ws + off_edata);
        unsigned short* embb = (unsigned short*)(ws + off_embb);
        unsigned short* xb  = (unsigned short*)(ws + off_xb);
        unsigned short* W0f = (unsigned short*)(ws + off_w0);
        unsigned short* W1f = (unsigned short*)(ws + off_w1);
        unsigned short* W2f = (unsigned short*)(ws + off_w2);

        // fused prep: zero counts + emb->bf16 + weight fragment-major pack
        int zb = (M / 4 + 255) / 256;
        int cb = ((M * EMB) / 4 + 255) / 256;
        int prep_blocks = zb + cb + 8 + 32 + 32;
        prep_kernel<<<prep_blocks, 256, 0, stream>>>(
            emb, W0, W1, W2, counts, embb, W0f, W1f, W2f, M, zb, cb);

        // CSR build
        hist_kernel<<<(E / 4 + 255) / 256, 256, 0, stream>>>(row, counts, E);
        int nb = (M + 1023) / 1024;
        scan_phase1<<<nb, 256, 0, stream>>>(counts, offs, bsums, M);
        scan_phase2<<<1, 256, 0, stream>>>(bsums, nb);
        scan_phase3<<<(M + 255) / 256, 256, 0, stream>>>(offs, bsums, cursor, M);
        scatter_kernel<<<(E + 255) / 256, 256, 0, stream>>>(row, col, val, cursor, edata, E);

        // pull SpMM -> xb (bf16): grid-stride, 8 rows/wave
        int pull_blocks = (M + 4 * ROWS_PER_WAVE - 1) / (4 * ROWS_PER_WAVE);
        pull_kernel<<<pull_blocks, 256, 0, stream>>>(offs, counts, edata, embb, xb, M);

        // fused 3-layer MLP -> out (BM=32)
        int gblocks = (M + 31) / 32;
        mlp_fused<<<gblocks, 256, 0, stream>>>(xb, W0f, W1f, W2f, out, M);
    } else {
        // fp32 fallback (ws too small): atomic scatter SpMM + fp32 GEMMs
        float* x = (float*)ws;
        (void)hipMemsetAsync(x, 0, (size_t)M * EMB * sizeof(float), stream);
        spmm_kernel<<<(E + 3) / 4, 256, 0, stream>>>(row, col, val, emb, x, E);
        int gblocks = (M + 63) / 64;
        gemm_f32<EMB, true ><<<gblocks, 256, 0, stream>>>(x,   W0, out, M);
        gemm_f32<HID, true ><<<gblocks, 256, 0, stream>>>(out, W1, out, M);
        gemm_f32<HID, false><<<gblocks, 256, 0, stream>>>(out, W2, out, M);
    }
}